// Round 2
// baseline (273.296 us; speedup 1.0000x reference)
//
#include <hip/hip_runtime.h>
#include <hip/hip_bf16.h>

// Shapes: B=32 S=1024 D=256 V=50257 C=1000   (float tensors fp32; x int32; out fp32)
// conv1: groups=256, Cin/g=1, Cout/g=6, K=7, pad=6 -> L1=1030; fold -> 768 ch
// kmax k1=515 -> tanh -> conv2: groups=128, Cin/g=6, Cout/g=14, K=5, pad=4 -> L2=519
// fold -> 896 ch -> kmax 4 -> tanh -> (32,3584) @ wf^T(1000,3584) + bf
//
// R9 = R8 (MFMA conv2, failed absmax 1.82e-2 vs 1.73e-2 -- precision, not mapping)
// with split-precision MFMA: F kept fp32 in LDS; per-tile in-register split of both
// operands into bf16 hi+lo, 3 cross products (Ah*Bh + Ah*Bl + Al*Bh). Conv2 error
// drops to ~1e-4 abs. 6 MFMAs + ~60 VALU per 16-col tile, <=3 tiles/wave -- still
// ~8x less issue pressure than R7's 540 scalar FMA + 156 ds_read per lane.
// OUT stride 528->532 (write bank conflicts 4-way -> 2-way = free).

typedef __attribute__((ext_vector_type(8))) short short8;
typedef __attribute__((ext_vector_type(4))) float f32x4;

__device__ __forceinline__ float fast_tanh(float x) {
    float e = __expf(2.f * x);          // tanh = 1 - 2/(e^{2x}+1); saturates at +-inf
    return 1.f - 2.f / (e + 1.f);
}

__device__ __forceinline__ unsigned fkey(float f) {
    unsigned u = __float_as_uint(f);
    return (u & 0x80000000u) ? ~u : (u | 0x80000000u);   // monotone order-preserving key
}

__device__ __forceinline__ float fkey_inv(unsigned k) {
    unsigned u = (k & 0x80000000u) ? (k ^ 0x80000000u) : ~k;
    return __uint_as_float(u);
}

__device__ __forceinline__ unsigned short f2bf_rne(float f) {
    unsigned u = __float_as_uint(f);
    return (unsigned short)((u + 0x7fffu + ((u >> 16) & 1u)) >> 16);
}

// ---------------- Stage 0: coalesced gather -> E2[b][p 0..63][l 0..1023][4ch] fp32 ----
// grid = 32*16 (b, 64-token chunk), 256 thr. Wave reads one 1 KB emb row; lane p keeps
// channels 4p..4p+3 (plane p). Per-lane stores form contiguous 256 B runs.
__global__ __launch_bounds__(256) void gather_kernel(
    const int* __restrict__ x, const float* __restrict__ emb, float* __restrict__ E2)
{
    const int b = blockIdx.x >> 4;
    const int c64 = blockIdx.x & 15;
    const int wv = threadIdx.x >> 6, lane = threadIdx.x & 63;
    float* dst = E2 + ((((size_t)b << 6) + lane) << 12);   // plane (b,lane): 1024*4 floats
#pragma unroll
    for (int t = 0; t < 16; ++t) {
        int l = (c64 << 6) + (wv << 4) + t;
        int tok = x[(b << 10) + l];                         // wave-uniform -> scalar load
        float4 v = *(const float4*)(emb + ((size_t)tok << 8) + (lane << 2));  // 1 KB/wave
        *(float4*)(dst + (size_t)l * 4) = v;
    }
}

// ---------------- Fused: conv1 + fold + kmax(515) + tanh + conv2(MFMA) + fold + kmax(4) + tanh ----
// grid = 32*64 blocks (b, r2), 896 threads = 14 waves.
__global__ __launch_bounds__(896) void stage12_kernel(
    const int* __restrict__ x, const float* __restrict__ emb,
    const float* __restrict__ w1, const float* __restrict__ b1,
    const float* __restrict__ w2, const float* __restrict__ b2,
    const float* __restrict__ E2,                   // null -> fallback direct gather
    __hip_bfloat16* __restrict__ H)
{
    // Region X: e[4*1104] f32 during phases A/B; OUT[16][532] f32 during phase C.
    __shared__ __align__(16) float X[8512];
    __shared__ __align__(16) float F[12 * 536];     // fp32, [4+pos], pos<515 valid
    const int b = blockIdx.x >> 6;
    const int r2 = blockIdx.x & 63;
    const int tid = threadIdx.x;
    float* e = X;

    // Phase A: zero F, fill e. E2 path: contiguous float4 per thread (coalesced).
    for (int i = tid; i < 12 * 536; i += 896) F[i] = 0.f;
    if (E2) {
        const float* E2blk = E2 + ((((size_t)b << 6) + r2) << 12);
        for (int idx = tid; idx < 1104; idx += 896) {
            int l = idx - 6;
            float4 v = {0.f, 0.f, 0.f, 0.f};
            if (l >= 0 && l < 1024) v = *(const float4*)(E2blk + (size_t)l * 4);
            e[0 * 1104 + idx] = v.x; e[1 * 1104 + idx] = v.y;
            e[2 * 1104 + idx] = v.z; e[3 * 1104 + idx] = v.w;
        }
    } else {
        for (int idx = tid; idx < 1104; idx += 896) {
            int l = idx - 6;
            float4 v = {0.f, 0.f, 0.f, 0.f};
            if (l >= 0 && l < 1024) {
                int tok = x[(b << 10) + l];
                v = *(const float4*)(emb + ((size_t)tok << 8) + (r2 << 2));
            }
            e[0 * 1104 + idx] = v.x; e[1 * 1104 + idx] = v.y;
            e[2 * 1104 + idx] = v.z; e[3 * 1104 + idx] = v.w;
        }
    }
    __syncthreads();

    const int w = tid >> 6;
    const int lane = tid & 63;

    // Phase B: waves 0..11 -> folded conv1 row i=w, exact radix-select 515, tanh -> F
    if (w < 12) {
        const int half = (w >= 6) ? 1 : 0;
        const int f = w - half * 6;
        const float* ep0 = e + (2 * half) * 1104;     // emb ch 4*r2 + 2*half
        const float* ep1 = ep0 + 1104;
        const int c0 = __builtin_amdgcn_readfirstlane((2 * (2 * r2 + half)) * 6 + f);
        const int c1 = c0 + 6;
        float wA[7], wB[7];
#pragma unroll
        for (int t = 0; t < 7; ++t) { wA[t] = w1[c0 * 7 + t]; wB[t] = w1[c1 * 7 + t]; }
        const float bias = b1[c0] + b1[c1];

        const int pos0 = lane * 17;                   // 17 contiguous outputs/lane
        float a0[7], a1[7];                           // rolling window (LDS-fed, branchless)
#pragma unroll
        for (int t = 0; t < 7; ++t) { a0[t] = ep0[pos0 + t]; a1[t] = ep1[pos0 + t]; }

        unsigned key[17];
#pragma unroll
        for (int j = 0; j < 17; ++j) {
            float a = bias;
#pragma unroll
            for (int t = 0; t < 7; ++t) a += a0[t] * wA[t] + a1[t] * wB[t];
            key[j] = (pos0 + j < 1030) ? fkey(a) : 0u;    // pads below any real key
            if (j < 16) {
#pragma unroll
                for (int t = 0; t < 6; ++t) { a0[t] = a0[t + 1]; a1[t] = a1[t + 1]; }
                a0[6] = ep0[pos0 + j + 7];
                a1[6] = ep1[pos0 + j + 7];
            }
        }

        // exact radix-select of 515th-largest key; early exit when the set separates
        unsigned T = 0u;
        for (int bit = 31; bit >= 0; --bit) {
            unsigned cand = T | (1u << bit);
            int cnt = 0;
#pragma unroll
            for (int j = 0; j < 17; ++j) cnt += (int)__popcll(__ballot(key[j] >= cand));
            if (cnt >= 515) T = cand;
            if (cnt == 515) break;
        }

        // order-preserving compaction: all >T plus first (515-#gt) ==T in index order
        const unsigned long long lm = (1ull << lane) - 1ull;
        int gt_tot = 0, gt_run = 0, eq_run = 0;
#pragma unroll
        for (int j = 0; j < 17; ++j) {
            unsigned long long bg = __ballot(key[j] > T);
            unsigned long long be = __ballot(key[j] == T);
            gt_tot += (int)__popcll(bg);
            gt_run += (int)__popcll(bg & lm);
            eq_run += (int)__popcll(be & lm);
        }
        const int q = 515 - gt_tot;
        float* Frow = F + w * 536;
#pragma unroll
        for (int j = 0; j < 17; ++j) {
            bool isgt = key[j] > T;
            bool iseq = key[j] == T;
            int pos = gt_run + (eq_run < q ? eq_run : q);
            if (isgt || (iseq && eq_run < q)) Frow[4 + pos] = fast_tanh(fkey_inv(key[j]));
            gt_run += isgt ? 1 : 0;
            eq_run += iseq ? 1 : 0;
        }
    }
    __syncthreads();

    // Phase C1: conv2+fold via split-precision MFMA. OUT[j][p] = sum_{k<60} A[j][k]*B[k][p]
    // k-slot (q,mm): row i = 3q + mm/5, tap t = mm%5 (mm=15 zero pad); same map for A,B.
    // Lane map (verified vs stage3): A row / B col = lane&15; k-quad = lane>>4;
    // D: row = (lane>>4)*4 + r (= channel), col = lane&15 (= position).
    const int jA = lane & 15;
    const int q3 = lane >> 4;
    float* OUT = X;
    short8 Ah0, Ah1, Al0, Al1;
    {
        float wt[16];
#pragma unroll
        for (int mm = 0; mm < 16; ++mm) {
            float v = 0.f;
            if (mm < 15 && jA < 14) {
                const int irow = 3 * q3 + mm / 5;          // mm/5, mm%5 compile-time
                const int t = mm % 5;
                const int h2 = (irow >= 6) ? 1 : 0;
                v = w2[(((2 * r2 + h2) * 14 + jA) * 6 + (irow - 6 * h2)) * 5 + t];
            }
            wt[mm] = v;
        }
#pragma unroll
        for (int m = 0; m < 8; ++m) {
            unsigned short h0 = f2bf_rne(wt[m]);
            float fh0 = __uint_as_float((unsigned)h0 << 16);
            Ah0[m] = (short)h0;
            Al0[m] = (short)f2bf_rne(wt[m] - fh0);
            unsigned short h1 = f2bf_rne(wt[8 + m]);
            float fh1 = __uint_as_float((unsigned)h1 << 16);
            Ah1[m] = (short)h1;
            Al1[m] = (short)f2bf_rne(wt[8 + m] - fh1);
        }
    }
    for (int tile = w; tile < 33; tile += 14) {            // 33 col-tiles over 14 waves
        const int p0 = tile << 4;
        const int bidx = (3 * q3) * 536 + p0 + jA;         // per-lane base; offsets imm
        float fv[16];
#pragma unroll
        for (int mm = 0; mm < 15; ++mm) fv[mm] = F[bidx + (mm / 5) * 536 + (mm % 5)];
        fv[15] = 0.f;
        short8 Bh0, Bh1, Bl0, Bl1;
#pragma unroll
        for (int m = 0; m < 8; ++m) {
            unsigned short h0 = f2bf_rne(fv[m]);
            float fh0 = __uint_as_float((unsigned)h0 << 16);
            Bh0[m] = (short)h0;
            Bl0[m] = (short)f2bf_rne(fv[m] - fh0);
            unsigned short h1 = f2bf_rne(fv[8 + m]);
            float fh1 = __uint_as_float((unsigned)h1 << 16);
            Bh1[m] = (short)h1;
            Bl1[m] = (short)f2bf_rne(fv[8 + m] - fh1);
        }
        f32x4 d0 = {0.f, 0.f, 0.f, 0.f};
        d0 = __builtin_amdgcn_mfma_f32_16x16x32_bf16(Ah0, Bh0, d0, 0, 0, 0);
        d0 = __builtin_amdgcn_mfma_f32_16x16x32_bf16(Ah1, Bh1, d0, 0, 0, 0);
        d0 = __builtin_amdgcn_mfma_f32_16x16x32_bf16(Ah0, Bl0, d0, 0, 0, 0);
        d0 = __builtin_amdgcn_mfma_f32_16x16x32_bf16(Ah1, Bl1, d0, 0, 0, 0);
        d0 = __builtin_amdgcn_mfma_f32_16x16x32_bf16(Al0, Bh0, d0, 0, 0, 0);
        d0 = __builtin_amdgcn_mfma_f32_16x16x32_bf16(Al1, Bh1, d0, 0, 0, 0);
        float* orow = OUT + (q3 * 4) * 532 + p0 + jA;
#pragma unroll
        for (int r = 0; r < 4; ++r) orow[r * 532] = d0[r]; // rows 14,15 unused scratch
    }
    __syncthreads();

    // Phase C2: wave w = channel j: kmax4 over OUT[j][0..519) + bias + tanh -> H
    {
        const int j = w;
        const int base = lane * 9;                            // 9 outputs/lane, 576 >= 519
        const int bidx2 = __builtin_amdgcn_readfirstlane((2 * r2) * 14 + j);
        const float bias2 = b2[bidx2] + b2[bidx2 + 14];       // uniform shift: select-safe
        float vv[9];
#pragma unroll
        for (int jj = 0; jj < 9; ++jj)
            vv[jj] = (base + jj < 519) ? OUT[j * 532 + base + jj] : -INFINITY;
        float sv[4]; int si[4];
#pragma unroll
        for (int it = 0; it < 4; ++it) {
            float m = vv[0]; int mi = base;
#pragma unroll
            for (int jj = 1; jj < 9; ++jj) { if (vv[jj] > m) { m = vv[jj]; mi = base + jj; } }
#pragma unroll
            for (int d = 1; d < 64; d <<= 1) {
                float om = __shfl_xor(m, d, 64);
                int omi = __shfl_xor(mi, d, 64);
                if (om > m || (om == m && omi < mi)) { m = om; mi = omi; }
            }
            sv[it] = m; si[it] = mi;
            int lj = mi - base;
#pragma unroll
            for (int jj = 0; jj < 9; ++jj) if (jj == lj) vv[jj] = -INFINITY;
        }
#define CSWAP(a, bq) { if (si[a] > si[bq]) { int ti = si[a]; si[a] = si[bq]; si[bq] = ti; \
                                             float tv = sv[a]; sv[a] = sv[bq]; sv[bq] = tv; } }
        CSWAP(0, 1) CSWAP(2, 3) CSWAP(0, 2) CSWAP(1, 3) CSWAP(1, 2)
#undef CSWAP
        if (lane == 0) {
            __hip_bfloat16* op = H + (size_t)b * 3584 + (r2 * 14 + j) * 4;
#pragma unroll
            for (int k = 0; k < 4; ++k) op[k] = __float2bfloat16(fast_tanh(sv[k] + bias2));
        }
    }
}

// ---------------- Stage 3: (32x3584) @ wf^T (3584x1000) + bf via MFMA, K split 4 ways ----------------
__global__ __launch_bounds__(256) void bias_init_kernel(
    const float* __restrict__ bfv, float* __restrict__ out)
{
    int idx = blockIdx.x * 256 + threadIdx.x;
    if (idx < 32000) out[idx] = bfv[idx - (idx / 1000) * 1000];
}

__global__ __launch_bounds__(256) void stage3_kernel(
    const __hip_bfloat16* __restrict__ Hb, const float* __restrict__ wf,
    float* __restrict__ out)
{
    __shared__ __align__(16) float sred[2 * 4 * 256];
    const int nt = blockIdx.x % 63;
    const int kc = blockIdx.x / 63;
    const int w = threadIdx.x >> 6, lane = threadIdx.x & 63;
    const int row = lane & 15, quad = lane >> 4;
    const int c = nt * 16 + row;
    const bool cvalid = (c < 1000);
    const int kofs = kc * 896 + w * 224 + quad * 8;
    const __hip_bfloat16* ap0 = Hb + (size_t)row * 3584 + kofs;
    const __hip_bfloat16* ap1 = ap0 + (size_t)16 * 3584;
    const float* bp = wf + (size_t)(cvalid ? c : 0) * 3584 + kofs;

    f32x4 acc0 = {0.f, 0.f, 0.f, 0.f};
    f32x4 acc1 = {0.f, 0.f, 0.f, 0.f};
#pragma unroll
    for (int it = 0; it < 7; ++it) {
        short8 a0 = *(const short8*)(ap0 + it * 32);
        short8 a1 = *(const short8*)(ap1 + it * 32);
        float4 p0 = *(const float4*)(bp + it * 32);
        float4 p1 = *(const float4*)(bp + it * 32 + 4);
        short8 bfr;
        bfr[0] = (short)f2bf_rne(p0.x); bfr[1] = (short)f2bf_rne(p0.y);
        bfr[2] = (short)f2bf_rne(p0.z); bfr[3] = (short)f2bf_rne(p0.w);
        bfr[4] = (short)f2bf_rne(p1.x); bfr[5] = (short)f2bf_rne(p1.y);
        bfr[6] = (short)f2bf_rne(p1.z); bfr[7] = (short)f2bf_rne(p1.w);
        if (!cvalid) bfr = short8{0, 0, 0, 0, 0, 0, 0, 0};
        acc0 = __builtin_amdgcn_mfma_f32_16x16x32_bf16(a0, bfr, acc0, 0, 0, 0);
        acc1 = __builtin_amdgcn_mfma_f32_16x16x32_bf16(a1, bfr, acc1, 0, 0, 0);
    }
#pragma unroll
    for (int r_ = 0; r_ < 4; ++r_) {
        sred[(0 * 4 + w) * 256 + lane * 4 + r_] = acc0[r_];
        sred[(1 * 4 + w) * 256 + lane * 4 + r_] = acc1[r_];
    }
    __syncthreads();
    if (threadIdx.x < 128) {
        const int mt = threadIdx.x >> 6;
        const int l2 = threadIdx.x & 63;
        const int rr = l2 & 15, qq = l2 >> 4;
        const int cc = nt * 16 + rr;
        if (cc < 1000) {
            const float* sp = sred + mt * 4 * 256;
#pragma unroll
            for (int r_ = 0; r_ < 4; ++r_) {
                float s = sp[0 * 256 + l2 * 4 + r_] + sp[1 * 256 + l2 * 4 + r_]
                        + sp[2 * 256 + l2 * 4 + r_] + sp[3 * 256 + l2 * 4 + r_];
                int brow = mt * 16 + qq * 4 + r_;
                atomicAdd(&out[brow * 1000 + cc], s);
            }
        }
    }
}

extern "C" void kernel_launch(void* const* d_in, const int* in_sizes, int n_in,
                              void* d_out, int out_size, void* d_ws, size_t ws_size,
                              hipStream_t stream) {
    const int* x      = (const int*)d_in[0];
    const float* emb  = (const float*)d_in[1];
    const float* w1   = (const float*)d_in[2];
    const float* b1   = (const float*)d_in[3];
    const float* w2   = (const float*)d_in[4];
    const float* b2   = (const float*)d_in[5];
    const float* wf   = (const float*)d_in[6];
    const float* bfv  = (const float*)d_in[7];

    const size_t E2_BYTES = (size_t)32 * 64 * 1024 * 4 * 4;   // 33,554,432 (fp32)
    const size_t H_BYTES  = (size_t)32 * 3584 * 2;            // 229,376
    float* E2 = nullptr;
    __hip_bfloat16* H;
    if (ws_size >= E2_BYTES + H_BYTES) {
        E2 = (float*)d_ws;
        H = (__hip_bfloat16*)((char*)d_ws + E2_BYTES);
    } else {
        H = (__hip_bfloat16*)d_ws;
    }

    bias_init_kernel<<<125, 256, 0, stream>>>(bfv, (float*)d_out);
    if (E2) gather_kernel<<<32 * 16, 256, 0, stream>>>(x, emb, E2);
    stage12_kernel<<<32 * 64, 896, 0, stream>>>(x, emb, w1, b1, w2, b2, E2, H);
    stage3_kernel<<<63 * 4, 256, 0, stream>>>(H, wf, (float*)d_out);
}

// Round 3
// 270.946 us; speedup vs baseline: 1.0087x; 1.0087x over previous
//
#include <hip/hip_runtime.h>
#include <hip/hip_bf16.h>

// Shapes: B=32 S=1024 D=256 V=50257 C=1000   (float tensors fp32; x int32; out fp32)
// conv1: groups=256, Cin/g=1, Cout/g=6, K=7, pad=6 -> L1=1030; fold -> 768 ch
// kmax k1=515 -> tanh -> conv2: groups=128, Cin/g=6, Cout/g=14, K=5, pad=4 -> L2=519
// fold -> 896 ch -> kmax 4 -> tanh -> (32,3584) @ wf^T(1000,3584) + bf
//
// R10 = R9 (stage12 172->159 us via split-precision MFMA conv2) + pipeline shrink:
// non-stage12 remainder was ~114 us (gather_kernel + E2 round-trip + bias_init +
// stage3 atomics + 3 launch gaps). (1) E2 pre-gather dropped: direct emb gather in
// phase A with register prefetch overlapping the F-zero loop; 64 blocks/b share rows
// (L2/L3-hot, emb 51MB < 256MB L3). (2) stage3 does full K per block (126 blocks =
// 63 col-tiles x 2 M-halves, 4 waves x 28 MFMA its + LDS reduce) and adds bias
// directly: no bias_init, no atomics. 4 kernels -> 2.

typedef __attribute__((ext_vector_type(8))) short short8;
typedef __attribute__((ext_vector_type(4))) float f32x4;

__device__ __forceinline__ float fast_tanh(float x) {
    float e = __expf(2.f * x);          // tanh = 1 - 2/(e^{2x}+1); saturates at +-inf
    return 1.f - 2.f / (e + 1.f);
}

__device__ __forceinline__ unsigned fkey(float f) {
    unsigned u = __float_as_uint(f);
    return (u & 0x80000000u) ? ~u : (u | 0x80000000u);   // monotone order-preserving key
}

__device__ __forceinline__ float fkey_inv(unsigned k) {
    unsigned u = (k & 0x80000000u) ? (k ^ 0x80000000u) : ~k;
    return __uint_as_float(u);
}

__device__ __forceinline__ unsigned short f2bf_rne(float f) {
    unsigned u = __float_as_uint(f);
    return (unsigned short)((u + 0x7fffu + ((u >> 16) & 1u)) >> 16);
}

// ---------------- Fused: gather + conv1 + fold + kmax(515) + tanh + conv2(MFMA) + fold + kmax(4) + tanh ----
// grid = 32*64 blocks (b, r2), 896 threads = 14 waves.
__global__ __launch_bounds__(896) void stage12_kernel(
    const int* __restrict__ x, const float* __restrict__ emb,
    const float* __restrict__ w1, const float* __restrict__ b1,
    const float* __restrict__ w2, const float* __restrict__ b2,
    __hip_bfloat16* __restrict__ H)
{
    // Region X: e[4*1104] f32 during phases A/B; OUT[16][532] f32 during phase C.
    __shared__ __align__(16) float X[8512];
    __shared__ __align__(16) float F[12 * 536];     // fp32, [4+pos], pos<515 valid
    const int b = blockIdx.x >> 6;
    const int r2 = blockIdx.x & 63;
    const int tid = threadIdx.x;
    float* e = X;

    // Phase A: direct gather. Prefetch the <=2 scattered 16B emb loads into regs,
    // overlap their latency with the F zero-fill, then commit to LDS planes.
    {
        const int l0 = tid - 6;
        const int l1 = tid + 890;                   // (tid+896) - 6
        float4 v0 = {0.f, 0.f, 0.f, 0.f}, v1 = {0.f, 0.f, 0.f, 0.f};
        if (l0 >= 0 && l0 < 1024) {
            int t0 = x[(b << 10) + l0];
            v0 = *(const float4*)(emb + ((size_t)t0 << 8) + (r2 << 2));
        }
        if (tid < 208 && l1 < 1024) {
            int t1 = x[(b << 10) + l1];
            v1 = *(const float4*)(emb + ((size_t)t1 << 8) + (r2 << 2));
        }
        for (int i = tid; i < 12 * 536; i += 896) F[i] = 0.f;
        e[0 * 1104 + tid] = v0.x; e[1 * 1104 + tid] = v0.y;
        e[2 * 1104 + tid] = v0.z; e[3 * 1104 + tid] = v0.w;
        if (tid < 208) {
            const int idx = tid + 896;
            e[0 * 1104 + idx] = v1.x; e[1 * 1104 + idx] = v1.y;
            e[2 * 1104 + idx] = v1.z; e[3 * 1104 + idx] = v1.w;
        }
    }
    __syncthreads();

    const int w = tid >> 6;
    const int lane = tid & 63;

    // Phase B: waves 0..11 -> folded conv1 row i=w, exact radix-select 515, tanh -> F
    if (w < 12) {
        const int half = (w >= 6) ? 1 : 0;
        const int f = w - half * 6;
        const float* ep0 = e + (2 * half) * 1104;     // emb ch 4*r2 + 2*half
        const float* ep1 = ep0 + 1104;
        const int c0 = __builtin_amdgcn_readfirstlane((2 * (2 * r2 + half)) * 6 + f);
        const int c1 = c0 + 6;
        float wA[7], wB[7];
#pragma unroll
        for (int t = 0; t < 7; ++t) { wA[t] = w1[c0 * 7 + t]; wB[t] = w1[c1 * 7 + t]; }
        const float bias = b1[c0] + b1[c1];

        const int pos0 = lane * 17;                   // 17 contiguous outputs/lane
        float a0[7], a1[7];                           // rolling window (LDS-fed, branchless)
#pragma unroll
        for (int t = 0; t < 7; ++t) { a0[t] = ep0[pos0 + t]; a1[t] = ep1[pos0 + t]; }

        unsigned key[17];
#pragma unroll
        for (int j = 0; j < 17; ++j) {
            float a = bias;
#pragma unroll
            for (int t = 0; t < 7; ++t) a += a0[t] * wA[t] + a1[t] * wB[t];
            key[j] = (pos0 + j < 1030) ? fkey(a) : 0u;    // pads below any real key
            if (j < 16) {
#pragma unroll
                for (int t = 0; t < 6; ++t) { a0[t] = a0[t + 1]; a1[t] = a1[t + 1]; }
                a0[6] = ep0[pos0 + j + 7];
                a1[6] = ep1[pos0 + j + 7];
            }
        }

        // exact radix-select of 515th-largest key; early exit when the set separates
        unsigned T = 0u;
        for (int bit = 31; bit >= 0; --bit) {
            unsigned cand = T | (1u << bit);
            int cnt = 0;
#pragma unroll
            for (int j = 0; j < 17; ++j) cnt += (int)__popcll(__ballot(key[j] >= cand));
            if (cnt >= 515) T = cand;
            if (cnt == 515) break;
        }

        // order-preserving compaction: all >T plus first (515-#gt) ==T in index order
        const unsigned long long lm = (1ull << lane) - 1ull;
        int gt_tot = 0, gt_run = 0, eq_run = 0;
#pragma unroll
        for (int j = 0; j < 17; ++j) {
            unsigned long long bg = __ballot(key[j] > T);
            unsigned long long be = __ballot(key[j] == T);
            gt_tot += (int)__popcll(bg);
            gt_run += (int)__popcll(bg & lm);
            eq_run += (int)__popcll(be & lm);
        }
        const int q = 515 - gt_tot;
        float* Frow = F + w * 536;
#pragma unroll
        for (int j = 0; j < 17; ++j) {
            bool isgt = key[j] > T;
            bool iseq = key[j] == T;
            int pos = gt_run + (eq_run < q ? eq_run : q);
            if (isgt || (iseq && eq_run < q)) Frow[4 + pos] = fast_tanh(fkey_inv(key[j]));
            gt_run += isgt ? 1 : 0;
            eq_run += iseq ? 1 : 0;
        }
    }
    __syncthreads();

    // Phase C1: conv2+fold via split-precision MFMA. OUT[j][p] = sum_{k<60} A[j][k]*B[k][p]
    // k-slot (q,mm): row i = 3q + mm/5, tap t = mm%5 (mm=15 zero pad); same map for A,B.
    // Lane map (verified vs stage3): A row / B col = lane&15; k-quad = lane>>4;
    // D: row = (lane>>4)*4 + r (= channel), col = lane&15 (= position).
    const int jA = lane & 15;
    const int q3 = lane >> 4;
    float* OUT = X;
    short8 Ah0, Ah1, Al0, Al1;
    {
        float wt[16];
#pragma unroll
        for (int mm = 0; mm < 16; ++mm) {
            float v = 0.f;
            if (mm < 15 && jA < 14) {
                const int irow = 3 * q3 + mm / 5;          // mm/5, mm%5 compile-time
                const int t = mm % 5;
                const int h2 = (irow >= 6) ? 1 : 0;
                v = w2[(((2 * r2 + h2) * 14 + jA) * 6 + (irow - 6 * h2)) * 5 + t];
            }
            wt[mm] = v;
        }
#pragma unroll
        for (int m = 0; m < 8; ++m) {
            unsigned short h0 = f2bf_rne(wt[m]);
            float fh0 = __uint_as_float((unsigned)h0 << 16);
            Ah0[m] = (short)h0;
            Al0[m] = (short)f2bf_rne(wt[m] - fh0);
            unsigned short h1 = f2bf_rne(wt[8 + m]);
            float fh1 = __uint_as_float((unsigned)h1 << 16);
            Ah1[m] = (short)h1;
            Al1[m] = (short)f2bf_rne(wt[8 + m] - fh1);
        }
    }
    for (int tile = w; tile < 33; tile += 14) {            // 33 col-tiles over 14 waves
        const int p0 = tile << 4;
        const int bidx = (3 * q3) * 536 + p0 + jA;         // per-lane base; offsets imm
        float fv[16];
#pragma unroll
        for (int mm = 0; mm < 15; ++mm) fv[mm] = F[bidx + (mm / 5) * 536 + (mm % 5)];
        fv[15] = 0.f;
        short8 Bh0, Bh1, Bl0, Bl1;
#pragma unroll
        for (int m = 0; m < 8; ++m) {
            unsigned short h0 = f2bf_rne(fv[m]);
            float fh0 = __uint_as_float((unsigned)h0 << 16);
            Bh0[m] = (short)h0;
            Bl0[m] = (short)f2bf_rne(fv[m] - fh0);
            unsigned short h1 = f2bf_rne(fv[8 + m]);
            float fh1 = __uint_as_float((unsigned)h1 << 16);
            Bh1[m] = (short)h1;
            Bl1[m] = (short)f2bf_rne(fv[8 + m] - fh1);
        }
        f32x4 d0 = {0.f, 0.f, 0.f, 0.f};
        d0 = __builtin_amdgcn_mfma_f32_16x16x32_bf16(Ah0, Bh0, d0, 0, 0, 0);
        d0 = __builtin_amdgcn_mfma_f32_16x16x32_bf16(Ah1, Bh1, d0, 0, 0, 0);
        d0 = __builtin_amdgcn_mfma_f32_16x16x32_bf16(Ah0, Bl0, d0, 0, 0, 0);
        d0 = __builtin_amdgcn_mfma_f32_16x16x32_bf16(Ah1, Bl1, d0, 0, 0, 0);
        d0 = __builtin_amdgcn_mfma_f32_16x16x32_bf16(Al0, Bh0, d0, 0, 0, 0);
        d0 = __builtin_amdgcn_mfma_f32_16x16x32_bf16(Al1, Bh1, d0, 0, 0, 0);
        float* orow = OUT + (q3 * 4) * 532 + p0 + jA;
#pragma unroll
        for (int r = 0; r < 4; ++r) orow[r * 532] = d0[r]; // rows 14,15 unused scratch
    }
    __syncthreads();

    // Phase C2: wave w = channel j: kmax4 over OUT[j][0..519) + bias + tanh -> H
    {
        const int j = w;
        const int base = lane * 9;                            // 9 outputs/lane, 576 >= 519
        const int bidx2 = __builtin_amdgcn_readfirstlane((2 * r2) * 14 + j);
        const float bias2 = b2[bidx2] + b2[bidx2 + 14];       // uniform shift: select-safe
        float vv[9];
#pragma unroll
        for (int jj = 0; jj < 9; ++jj)
            vv[jj] = (base + jj < 519) ? OUT[j * 532 + base + jj] : -INFINITY;
        float sv[4]; int si[4];
#pragma unroll
        for (int it = 0; it < 4; ++it) {
            float m = vv[0]; int mi = base;
#pragma unroll
            for (int jj = 1; jj < 9; ++jj) { if (vv[jj] > m) { m = vv[jj]; mi = base + jj; } }
#pragma unroll
            for (int d = 1; d < 64; d <<= 1) {
                float om = __shfl_xor(m, d, 64);
                int omi = __shfl_xor(mi, d, 64);
                if (om > m || (om == m && omi < mi)) { m = om; mi = omi; }
            }
            sv[it] = m; si[it] = mi;
            int lj = mi - base;
#pragma unroll
            for (int jj = 0; jj < 9; ++jj) if (jj == lj) vv[jj] = -INFINITY;
        }
#define CSWAP(a, bq) { if (si[a] > si[bq]) { int ti = si[a]; si[a] = si[bq]; si[bq] = ti; \
                                             float tv = sv[a]; sv[a] = sv[bq]; sv[bq] = tv; } }
        CSWAP(0, 1) CSWAP(2, 3) CSWAP(0, 2) CSWAP(1, 3) CSWAP(1, 2)
#undef CSWAP
        if (lane == 0) {
            __hip_bfloat16* op = H + (size_t)b * 3584 + (r2 * 14 + j) * 4;
#pragma unroll
            for (int k = 0; k < 4; ++k) op[k] = __float2bfloat16(fast_tanh(sv[k] + bias2));
        }
    }
}

// ---------------- Stage 3: (32x3584) @ wf^T (3584x1000) + bf via MFMA, full K per block ----
// grid = 63 col-tiles x 2 M-halves = 126 blocks, 256 thr (4 waves split K, LDS reduce).
// Writes out = acc + bf directly: no bias_init kernel, no atomics.
__global__ __launch_bounds__(256) void stage3_kernel(
    const __hip_bfloat16* __restrict__ Hb, const float* __restrict__ wf,
    const float* __restrict__ bfv, float* __restrict__ out)
{
    __shared__ __align__(16) float sred[4 * 256];
    const int nt = blockIdx.x % 63;
    const int mh = blockIdx.x / 63;                 // 0..1: rows mh*16..mh*16+15
    const int w = threadIdx.x >> 6, lane = threadIdx.x & 63;
    const int row = lane & 15, quad = lane >> 4;
    const int c = nt * 16 + row;
    const bool cvalid = (c < 1000);
    const int kofs = w * 896 + quad * 8;
    const __hip_bfloat16* ap = Hb + (size_t)(mh * 16 + row) * 3584 + kofs;
    const float* bp = wf + (size_t)(cvalid ? c : 0) * 3584 + kofs;

    f32x4 acc = {0.f, 0.f, 0.f, 0.f};
#pragma unroll
    for (int it = 0; it < 28; ++it) {
        short8 a0 = *(const short8*)(ap + it * 32);
        float4 p0 = *(const float4*)(bp + it * 32);
        float4 p1 = *(const float4*)(bp + it * 32 + 4);
        short8 bfr;
        bfr[0] = (short)f2bf_rne(p0.x); bfr[1] = (short)f2bf_rne(p0.y);
        bfr[2] = (short)f2bf_rne(p0.z); bfr[3] = (short)f2bf_rne(p0.w);
        bfr[4] = (short)f2bf_rne(p1.x); bfr[5] = (short)f2bf_rne(p1.y);
        bfr[6] = (short)f2bf_rne(p1.z); bfr[7] = (short)f2bf_rne(p1.w);
        if (!cvalid) bfr = short8{0, 0, 0, 0, 0, 0, 0, 0};
        acc = __builtin_amdgcn_mfma_f32_16x16x32_bf16(a0, bfr, acc, 0, 0, 0);
    }
#pragma unroll
    for (int r_ = 0; r_ < 4; ++r_) sred[w * 256 + lane * 4 + r_] = acc[r_];
    __syncthreads();
    if (threadIdx.x < 64) {
        const int l2 = threadIdx.x;
        const int rr = l2 & 15, qq = l2 >> 4;
        const int cc = nt * 16 + rr;
        if (cc < 1000) {
            const float bias = bfv[cc];
#pragma unroll
            for (int r_ = 0; r_ < 4; ++r_) {
                float s = sred[0 * 256 + l2 * 4 + r_] + sred[1 * 256 + l2 * 4 + r_]
                        + sred[2 * 256 + l2 * 4 + r_] + sred[3 * 256 + l2 * 4 + r_];
                int brow = mh * 16 + qq * 4 + r_;
                out[brow * 1000 + cc] = s + bias;
            }
        }
    }
}

extern "C" void kernel_launch(void* const* d_in, const int* in_sizes, int n_in,
                              void* d_out, int out_size, void* d_ws, size_t ws_size,
                              hipStream_t stream) {
    const int* x      = (const int*)d_in[0];
    const float* emb  = (const float*)d_in[1];
    const float* w1   = (const float*)d_in[2];
    const float* b1   = (const float*)d_in[3];
    const float* w2   = (const float*)d_in[4];
    const float* b2   = (const float*)d_in[5];
    const float* wf   = (const float*)d_in[6];
    const float* bfv  = (const float*)d_in[7];

    __hip_bfloat16* H = (__hip_bfloat16*)d_ws;      // 32*3584*2 = 229,376 B

    stage12_kernel<<<32 * 64, 896, 0, stream>>>(x, emb, w1, b1, w2, b2, H);
    stage3_kernel<<<126, 256, 0, stream>>>(H, wf, bfv, (float*)d_out);
}

// Round 4
// 260.886 us; speedup vs baseline: 1.0476x; 1.0386x over previous
//
#include <hip/hip_runtime.h>
#include <hip/hip_bf16.h>

// Shapes: B=32 S=1024 D=256 V=50257 C=1000   (float tensors fp32; x int32; out fp32)
// conv1: groups=256, Cin/g=1, Cout/g=6, K=7, pad=6 -> L1=1030; fold -> 768 ch
// kmax k1=515 -> tanh -> conv2: groups=128, Cin/g=6, Cout/g=14, K=5, pad=4 -> L2=519
// fold -> 896 ch -> kmax 4 -> tanh -> (32,3584) @ wf^T(1000,3584) + bf
//
// R11 = R10 + XCD-contiguous block swizzle. R10 rocprof: FETCH_SIZE 122 MB vs 34 MB
// useful gather bytes -- adjacent r2 blocks (which share 64B emb lines) round-robin
// onto different XCDs, so each private L2 re-fetches the same lines (~4x line
// amplification, latency-bound phase A: +17us vs E2-coalesced). Swizzle
// logical = (hw&7)*256 + hw>>3 puts b in [4k,4k+4) x all r2 on XCD k: co-resident
// blocks share one batch's token rows; 64B lines serve 4 r2-neighbors from L2
// (~0.5MB hot window << 4MB XCD L2). Also: both x token loads issue before the
// dependent emb loads (one fewer serialized round-trip).

typedef __attribute__((ext_vector_type(8))) short short8;
typedef __attribute__((ext_vector_type(4))) float f32x4;

__device__ __forceinline__ float fast_tanh(float x) {
    float e = __expf(2.f * x);          // tanh = 1 - 2/(e^{2x}+1); saturates at +-inf
    return 1.f - 2.f / (e + 1.f);
}

__device__ __forceinline__ unsigned fkey(float f) {
    unsigned u = __float_as_uint(f);
    return (u & 0x80000000u) ? ~u : (u | 0x80000000u);   // monotone order-preserving key
}

__device__ __forceinline__ float fkey_inv(unsigned k) {
    unsigned u = (k & 0x80000000u) ? (k ^ 0x80000000u) : ~k;
    return __uint_as_float(u);
}

__device__ __forceinline__ unsigned short f2bf_rne(float f) {
    unsigned u = __float_as_uint(f);
    return (unsigned short)((u + 0x7fffu + ((u >> 16) & 1u)) >> 16);
}

// ---------------- Fused: gather + conv1 + fold + kmax(515) + tanh + conv2(MFMA) + fold + kmax(4) + tanh ----
// grid = 32*64 blocks (b, r2) after swizzle, 896 threads = 14 waves.
__global__ __launch_bounds__(896) void stage12_kernel(
    const int* __restrict__ x, const float* __restrict__ emb,
    const float* __restrict__ w1, const float* __restrict__ b1,
    const float* __restrict__ w2, const float* __restrict__ b2,
    __hip_bfloat16* __restrict__ H)
{
    // Region X: e[4*1104] f32 during phases A/B; OUT[16][532] f32 during phase C.
    __shared__ __align__(16) float X[8512];
    __shared__ __align__(16) float F[12 * 536];     // fp32, [4+pos], pos<515 valid
    const int hw = blockIdx.x;
    const int logical = ((hw & 7) << 8) | (hw >> 3);   // XCD k -> b in [4k,4k+4), all r2
    const int b = logical >> 6;
    const int r2 = logical & 63;
    const int tid = threadIdx.x;
    float* e = X;

    // Phase A: direct gather. Issue both x loads, then both scattered 16B emb loads,
    // overlap their latency with the F zero-fill, then commit to LDS planes.
    {
        const int l0 = tid - 6;
        const int l1 = tid + 890;                   // (tid+896) - 6
        int t0 = -1, t1 = -1;
        if (l0 >= 0 && l0 < 1024) t0 = x[(b << 10) + l0];
        if (tid < 208 && l1 < 1024) t1 = x[(b << 10) + l1];
        float4 v0 = {0.f, 0.f, 0.f, 0.f}, v1 = {0.f, 0.f, 0.f, 0.f};
        if (t0 >= 0) v0 = *(const float4*)(emb + ((size_t)t0 << 8) + (r2 << 2));
        if (t1 >= 0) v1 = *(const float4*)(emb + ((size_t)t1 << 8) + (r2 << 2));
        for (int i = tid; i < 12 * 536; i += 896) F[i] = 0.f;
        e[0 * 1104 + tid] = v0.x; e[1 * 1104 + tid] = v0.y;
        e[2 * 1104 + tid] = v0.z; e[3 * 1104 + tid] = v0.w;
        if (tid < 208) {
            const int idx = tid + 896;
            e[0 * 1104 + idx] = v1.x; e[1 * 1104 + idx] = v1.y;
            e[2 * 1104 + idx] = v1.z; e[3 * 1104 + idx] = v1.w;
        }
    }
    __syncthreads();

    const int w = tid >> 6;
    const int lane = tid & 63;

    // Phase B: waves 0..11 -> folded conv1 row i=w, exact radix-select 515, tanh -> F
    if (w < 12) {
        const int half = (w >= 6) ? 1 : 0;
        const int f = w - half * 6;
        const float* ep0 = e + (2 * half) * 1104;     // emb ch 4*r2 + 2*half
        const float* ep1 = ep0 + 1104;
        const int c0 = __builtin_amdgcn_readfirstlane((2 * (2 * r2 + half)) * 6 + f);
        const int c1 = c0 + 6;
        float wA[7], wB[7];
#pragma unroll
        for (int t = 0; t < 7; ++t) { wA[t] = w1[c0 * 7 + t]; wB[t] = w1[c1 * 7 + t]; }
        const float bias = b1[c0] + b1[c1];

        const int pos0 = lane * 17;                   // 17 contiguous outputs/lane
        float a0[7], a1[7];                           // rolling window (LDS-fed, branchless)
#pragma unroll
        for (int t = 0; t < 7; ++t) { a0[t] = ep0[pos0 + t]; a1[t] = ep1[pos0 + t]; }

        unsigned key[17];
#pragma unroll
        for (int j = 0; j < 17; ++j) {
            float a = bias;
#pragma unroll
            for (int t = 0; t < 7; ++t) a += a0[t] * wA[t] + a1[t] * wB[t];
            key[j] = (pos0 + j < 1030) ? fkey(a) : 0u;    // pads below any real key
            if (j < 16) {
#pragma unroll
                for (int t = 0; t < 6; ++t) { a0[t] = a0[t + 1]; a1[t] = a1[t + 1]; }
                a0[6] = ep0[pos0 + j + 7];
                a1[6] = ep1[pos0 + j + 7];
            }
        }

        // exact radix-select of 515th-largest key; early exit when the set separates
        unsigned T = 0u;
        for (int bit = 31; bit >= 0; --bit) {
            unsigned cand = T | (1u << bit);
            int cnt = 0;
#pragma unroll
            for (int j = 0; j < 17; ++j) cnt += (int)__popcll(__ballot(key[j] >= cand));
            if (cnt >= 515) T = cand;
            if (cnt == 515) break;
        }

        // order-preserving compaction: all >T plus first (515-#gt) ==T in index order
        const unsigned long long lm = (1ull << lane) - 1ull;
        int gt_tot = 0, gt_run = 0, eq_run = 0;
#pragma unroll
        for (int j = 0; j < 17; ++j) {
            unsigned long long bg = __ballot(key[j] > T);
            unsigned long long be = __ballot(key[j] == T);
            gt_tot += (int)__popcll(bg);
            gt_run += (int)__popcll(bg & lm);
            eq_run += (int)__popcll(be & lm);
        }
        const int q = 515 - gt_tot;
        float* Frow = F + w * 536;
#pragma unroll
        for (int j = 0; j < 17; ++j) {
            bool isgt = key[j] > T;
            bool iseq = key[j] == T;
            int pos = gt_run + (eq_run < q ? eq_run : q);
            if (isgt || (iseq && eq_run < q)) Frow[4 + pos] = fast_tanh(fkey_inv(key[j]));
            gt_run += isgt ? 1 : 0;
            eq_run += iseq ? 1 : 0;
        }
    }
    __syncthreads();

    // Phase C1: conv2+fold via split-precision MFMA. OUT[j][p] = sum_{k<60} A[j][k]*B[k][p]
    // k-slot (q,mm): row i = 3q + mm/5, tap t = mm%5 (mm=15 zero pad); same map for A,B.
    // Lane map (verified vs stage3): A row / B col = lane&15; k-quad = lane>>4;
    // D: row = (lane>>4)*4 + r (= channel), col = lane&15 (= position).
    const int jA = lane & 15;
    const int q3 = lane >> 4;
    float* OUT = X;
    short8 Ah0, Ah1, Al0, Al1;
    {
        float wt[16];
#pragma unroll
        for (int mm = 0; mm < 16; ++mm) {
            float v = 0.f;
            if (mm < 15 && jA < 14) {
                const int irow = 3 * q3 + mm / 5;          // mm/5, mm%5 compile-time
                const int t = mm % 5;
                const int h2 = (irow >= 6) ? 1 : 0;
                v = w2[(((2 * r2 + h2) * 14 + jA) * 6 + (irow - 6 * h2)) * 5 + t];
            }
            wt[mm] = v;
        }
#pragma unroll
        for (int m = 0; m < 8; ++m) {
            unsigned short h0 = f2bf_rne(wt[m]);
            float fh0 = __uint_as_float((unsigned)h0 << 16);
            Ah0[m] = (short)h0;
            Al0[m] = (short)f2bf_rne(wt[m] - fh0);
            unsigned short h1 = f2bf_rne(wt[8 + m]);
            float fh1 = __uint_as_float((unsigned)h1 << 16);
            Ah1[m] = (short)h1;
            Al1[m] = (short)f2bf_rne(wt[8 + m] - fh1);
        }
    }
    for (int tile = w; tile < 33; tile += 14) {            // 33 col-tiles over 14 waves
        const int p0 = tile << 4;
        const int bidx = (3 * q3) * 536 + p0 + jA;         // per-lane base; offsets imm
        float fv[16];
#pragma unroll
        for (int mm = 0; mm < 15; ++mm) fv[mm] = F[bidx + (mm / 5) * 536 + (mm % 5)];
        fv[15] = 0.f;
        short8 Bh0, Bh1, Bl0, Bl1;
#pragma unroll
        for (int m = 0; m < 8; ++m) {
            unsigned short h0 = f2bf_rne(fv[m]);
            float fh0 = __uint_as_float((unsigned)h0 << 16);
            Bh0[m] = (short)h0;
            Bl0[m] = (short)f2bf_rne(fv[m] - fh0);
            unsigned short h1 = f2bf_rne(fv[8 + m]);
            float fh1 = __uint_as_float((unsigned)h1 << 16);
            Bh1[m] = (short)h1;
            Bl1[m] = (short)f2bf_rne(fv[8 + m] - fh1);
        }
        f32x4 d0 = {0.f, 0.f, 0.f, 0.f};
        d0 = __builtin_amdgcn_mfma_f32_16x16x32_bf16(Ah0, Bh0, d0, 0, 0, 0);
        d0 = __builtin_amdgcn_mfma_f32_16x16x32_bf16(Ah1, Bh1, d0, 0, 0, 0);
        d0 = __builtin_amdgcn_mfma_f32_16x16x32_bf16(Ah0, Bl0, d0, 0, 0, 0);
        d0 = __builtin_amdgcn_mfma_f32_16x16x32_bf16(Ah1, Bl1, d0, 0, 0, 0);
        d0 = __builtin_amdgcn_mfma_f32_16x16x32_bf16(Al0, Bh0, d0, 0, 0, 0);
        d0 = __builtin_amdgcn_mfma_f32_16x16x32_bf16(Al1, Bh1, d0, 0, 0, 0);
        float* orow = OUT + (q3 * 4) * 532 + p0 + jA;
#pragma unroll
        for (int r = 0; r < 4; ++r) orow[r * 532] = d0[r]; // rows 14,15 unused scratch
    }
    __syncthreads();

    // Phase C2: wave w = channel j: kmax4 over OUT[j][0..519) + bias + tanh -> H
    {
        const int j = w;
        const int base = lane * 9;                            // 9 outputs/lane, 576 >= 519
        const int bidx2 = __builtin_amdgcn_readfirstlane((2 * r2) * 14 + j);
        const float bias2 = b2[bidx2] + b2[bidx2 + 14];       // uniform shift: select-safe
        float vv[9];
#pragma unroll
        for (int jj = 0; jj < 9; ++jj)
            vv[jj] = (base + jj < 519) ? OUT[j * 532 + base + jj] : -INFINITY;
        float sv[4]; int si[4];
#pragma unroll
        for (int it = 0; it < 4; ++it) {
            float m = vv[0]; int mi = base;
#pragma unroll
            for (int jj = 1; jj < 9; ++jj) { if (vv[jj] > m) { m = vv[jj]; mi = base + jj; } }
#pragma unroll
            for (int d = 1; d < 64; d <<= 1) {
                float om = __shfl_xor(m, d, 64);
                int omi = __shfl_xor(mi, d, 64);
                if (om > m || (om == m && omi < mi)) { m = om; mi = omi; }
            }
            sv[it] = m; si[it] = mi;
            int lj = mi - base;
#pragma unroll
            for (int jj = 0; jj < 9; ++jj) if (jj == lj) vv[jj] = -INFINITY;
        }
#define CSWAP(a, bq) { if (si[a] > si[bq]) { int ti = si[a]; si[a] = si[bq]; si[bq] = ti; \
                                             float tv = sv[a]; sv[a] = sv[bq]; sv[bq] = tv; } }
        CSWAP(0, 1) CSWAP(2, 3) CSWAP(0, 2) CSWAP(1, 3) CSWAP(1, 2)
#undef CSWAP
        if (lane == 0) {
            __hip_bfloat16* op = H + (size_t)b * 3584 + (r2 * 14 + j) * 4;
#pragma unroll
            for (int k = 0; k < 4; ++k) op[k] = __float2bfloat16(fast_tanh(sv[k] + bias2));
        }
    }
}

// ---------------- Stage 3: (32x3584) @ wf^T (3584x1000) + bf via MFMA, full K per block ----
// grid = 63 col-tiles x 2 M-halves = 126 blocks, 256 thr (4 waves split K, LDS reduce).
// Writes out = acc + bf directly: no bias_init kernel, no atomics.
__global__ __launch_bounds__(256) void stage3_kernel(
    const __hip_bfloat16* __restrict__ Hb, const float* __restrict__ wf,
    const float* __restrict__ bfv, float* __restrict__ out)
{
    __shared__ __align__(16) float sred[4 * 256];
    const int nt = blockIdx.x % 63;
    const int mh = blockIdx.x / 63;                 // 0..1: rows mh*16..mh*16+15
    const int w = threadIdx.x >> 6, lane = threadIdx.x & 63;
    const int row = lane & 15, quad = lane >> 4;
    const int c = nt * 16 + row;
    const bool cvalid = (c < 1000);
    const int kofs = w * 896 + quad * 8;
    const __hip_bfloat16* ap = Hb + (size_t)(mh * 16 + row) * 3584 + kofs;
    const float* bp = wf + (size_t)(cvalid ? c : 0) * 3584 + kofs;

    f32x4 acc = {0.f, 0.f, 0.f, 0.f};
#pragma unroll
    for (int it = 0; it < 28; ++it) {
        short8 a0 = *(const short8*)(ap + it * 32);
        float4 p0 = *(const float4*)(bp + it * 32);
        float4 p1 = *(const float4*)(bp + it * 32 + 4);
        short8 bfr;
        bfr[0] = (short)f2bf_rne(p0.x); bfr[1] = (short)f2bf_rne(p0.y);
        bfr[2] = (short)f2bf_rne(p0.z); bfr[3] = (short)f2bf_rne(p0.w);
        bfr[4] = (short)f2bf_rne(p1.x); bfr[5] = (short)f2bf_rne(p1.y);
        bfr[6] = (short)f2bf_rne(p1.z); bfr[7] = (short)f2bf_rne(p1.w);
        if (!cvalid) bfr = short8{0, 0, 0, 0, 0, 0, 0, 0};
        acc = __builtin_amdgcn_mfma_f32_16x16x32_bf16(a0, bfr, acc, 0, 0, 0);
    }
#pragma unroll
    for (int r_ = 0; r_ < 4; ++r_) sred[w * 256 + lane * 4 + r_] = acc[r_];
    __syncthreads();
    if (threadIdx.x < 64) {
        const int l2 = threadIdx.x;
        const int rr = l2 & 15, qq = l2 >> 4;
        const int cc = nt * 16 + rr;
        if (cc < 1000) {
            const float bias = bfv[cc];
#pragma unroll
            for (int r_ = 0; r_ < 4; ++r_) {
                float s = sred[0 * 256 + l2 * 4 + r_] + sred[1 * 256 + l2 * 4 + r_]
                        + sred[2 * 256 + l2 * 4 + r_] + sred[3 * 256 + l2 * 4 + r_];
                int brow = mh * 16 + qq * 4 + r_;
                out[brow * 1000 + cc] = s + bias;
            }
        }
    }
}

extern "C" void kernel_launch(void* const* d_in, const int* in_sizes, int n_in,
                              void* d_out, int out_size, void* d_ws, size_t ws_size,
                              hipStream_t stream) {
    const int* x      = (const int*)d_in[0];
    const float* emb  = (const float*)d_in[1];
    const float* w1   = (const float*)d_in[2];
    const float* b1   = (const float*)d_in[3];
    const float* w2   = (const float*)d_in[4];
    const float* b2   = (const float*)d_in[5];
    const float* wf   = (const float*)d_in[6];
    const float* bfv  = (const float*)d_in[7];

    __hip_bfloat16* H = (__hip_bfloat16*)d_ws;      // 32*3584*2 = 229,376 B

    stage12_kernel<<<32 * 64, 896, 0, stream>>>(x, emb, w1, b1, w2, b2, H);
    stage3_kernel<<<126, 256, 0, stream>>>(H, wf, bfv, (float*)d_out);
}

// Round 5
// 246.614 us; speedup vs baseline: 1.1082x; 1.0579x over previous
//
#include <hip/hip_runtime.h>
#include <hip/hip_bf16.h>

// Shapes: B=32 S=1024 D=256 V=50257 C=1000   (float tensors fp32; x int32; out fp32)
// conv1: groups=256, Cin/g=1, Cout/g=6, K=7, pad=6 -> L1=1030; fold -> 768 ch
// kmax k1=515 -> tanh -> conv2: groups=128, Cin/g=6, Cout/g=14, K=5, pad=4 -> L2=519
// fold -> 896 ch -> kmax 4 -> tanh -> (32,3584) @ wf^T(1000,3584) + bf
//
// R12 = R11 (169.5us stage12; XCD swizzle cut FETCH 122->17MB) + VALU diet.
// Accounting: ~4.3k VALU inst/thread; phase C1's per-read split-precision conversion
// (~1000 inst) was the biggest block. (1) F now stored as u32 (bf16hi<<16|bf16lo),
// split ONCE at phase-B write; C1 rebuilds fragments with 48 shift/or per tile
// (bit-identical MFMA inputs). (2) mbcnt replaces popcll(mask&lm) prefix counts.
// (3) A-fragment build hoisted before the barrier (idle waves 12/13 overlap it with
// phase B). (4) stage3 512 thr (8 waves x K=448) for 2x TLP at 1 block/CU.

typedef __attribute__((ext_vector_type(8))) short short8;
typedef __attribute__((ext_vector_type(4))) float f32x4;
typedef __attribute__((ext_vector_type(4))) int int4v;

union VPack { int4v i; short8 s; };

__device__ __forceinline__ float fast_tanh(float x) {
    float e = __expf(2.f * x);          // tanh = 1 - 2/(e^{2x}+1); saturates at +-inf
    return 1.f - 2.f / (e + 1.f);
}

__device__ __forceinline__ unsigned fkey(float f) {
    unsigned u = __float_as_uint(f);
    return (u & 0x80000000u) ? ~u : (u | 0x80000000u);   // monotone order-preserving key
}

__device__ __forceinline__ float fkey_inv(unsigned k) {
    unsigned u = (k & 0x80000000u) ? (k ^ 0x80000000u) : ~k;
    return __uint_as_float(u);
}

__device__ __forceinline__ unsigned f2bf_rne(float f) {
    unsigned u = __float_as_uint(f);
    return (u + 0x7fffu + ((u >> 16) & 1u)) >> 16;
}

// popcount of mask restricted to lanes below this lane (HW prefix-popcount)
__device__ __forceinline__ int prefix_cnt(unsigned long long m) {
    return (int)__builtin_amdgcn_mbcnt_hi((unsigned)(m >> 32),
                 __builtin_amdgcn_mbcnt_lo((unsigned)m, 0u));
}

// ---------------- Fused: gather + conv1 + fold + kmax(515) + tanh + conv2(MFMA) + fold + kmax(4) + tanh ----
// grid = 32*64 blocks (b, r2) after swizzle, 896 threads = 14 waves.
__global__ __launch_bounds__(896) void stage12_kernel(
    const int* __restrict__ x, const float* __restrict__ emb,
    const float* __restrict__ w1, const float* __restrict__ b1,
    const float* __restrict__ w2, const float* __restrict__ b2,
    __hip_bfloat16* __restrict__ H)
{
    // Region X: e[4*1104] f32 during phases A/B; OUT[16][532] f32 during phase C.
    __shared__ __align__(16) float X[8512];
    __shared__ __align__(16) unsigned F[12 * 536];  // bf16 hi<<16 | lo, [4+pos], pos<515
    const int hw = blockIdx.x;
    const int logical = ((hw & 7) << 8) | (hw >> 3);   // XCD k -> b in [4k,4k+4), all r2
    const int b = logical >> 6;
    const int r2 = logical & 63;
    const int tid = threadIdx.x;
    float* e = X;

    // Phase A: direct gather. Issue both x loads, then both scattered 16B emb loads,
    // overlap their latency with the F zero-fill, then commit to LDS planes.
    {
        const int l0 = tid - 6;
        const int l1 = tid + 890;                   // (tid+896) - 6
        int t0 = -1, t1 = -1;
        if (l0 >= 0 && l0 < 1024) t0 = x[(b << 10) + l0];
        if (tid < 208 && l1 < 1024) t1 = x[(b << 10) + l1];
        float4 v0 = {0.f, 0.f, 0.f, 0.f}, v1 = {0.f, 0.f, 0.f, 0.f};
        if (t0 >= 0) v0 = *(const float4*)(emb + ((size_t)t0 << 8) + (r2 << 2));
        if (t1 >= 0) v1 = *(const float4*)(emb + ((size_t)t1 << 8) + (r2 << 2));
        for (int i = tid; i < 12 * 536; i += 896) F[i] = 0u;
        e[0 * 1104 + tid] = v0.x; e[1 * 1104 + tid] = v0.y;
        e[2 * 1104 + tid] = v0.z; e[3 * 1104 + tid] = v0.w;
        if (tid < 208) {
            const int idx = tid + 896;
            e[0 * 1104 + idx] = v1.x; e[1 * 1104 + idx] = v1.y;
            e[2 * 1104 + idx] = v1.z; e[3 * 1104 + idx] = v1.w;
        }
    }
    __syncthreads();

    const int w = tid >> 6;
    const int lane = tid & 63;

    // Phase B: waves 0..11 -> folded conv1 row i=w, exact radix-select 515, tanh,
    // split to bf16 hi/lo, pack -> F (u32)
    if (w < 12) {
        const int half = (w >= 6) ? 1 : 0;
        const int f = w - half * 6;
        const float* ep0 = e + (2 * half) * 1104;     // emb ch 4*r2 + 2*half
        const float* ep1 = ep0 + 1104;
        const int c0 = __builtin_amdgcn_readfirstlane((2 * (2 * r2 + half)) * 6 + f);
        const int c1 = c0 + 6;
        float wA[7], wB[7];
#pragma unroll
        for (int t = 0; t < 7; ++t) { wA[t] = w1[c0 * 7 + t]; wB[t] = w1[c1 * 7 + t]; }
        const float bias = b1[c0] + b1[c1];

        const int pos0 = lane * 17;                   // 17 contiguous outputs/lane
        float a0[7], a1[7];                           // rolling window (LDS-fed, branchless)
#pragma unroll
        for (int t = 0; t < 7; ++t) { a0[t] = ep0[pos0 + t]; a1[t] = ep1[pos0 + t]; }

        unsigned key[17];
#pragma unroll
        for (int j = 0; j < 17; ++j) {
            float a = bias;
#pragma unroll
            for (int t = 0; t < 7; ++t) a += a0[t] * wA[t] + a1[t] * wB[t];
            key[j] = (pos0 + j < 1030) ? fkey(a) : 0u;    // pads below any real key
            if (j < 16) {
#pragma unroll
                for (int t = 0; t < 6; ++t) { a0[t] = a0[t + 1]; a1[t] = a1[t + 1]; }
                a0[6] = ep0[pos0 + j + 7];
                a1[6] = ep1[pos0 + j + 7];
            }
        }

        // exact radix-select of 515th-largest key; early exit when the set separates
        unsigned T = 0u;
        for (int bit = 31; bit >= 0; --bit) {
            unsigned cand = T | (1u << bit);
            int cnt = 0;
#pragma unroll
            for (int j = 0; j < 17; ++j) cnt += (int)__popcll(__ballot(key[j] >= cand));
            if (cnt >= 515) T = cand;
            if (cnt == 515) break;
        }

        // order-preserving compaction: all >T plus first (515-#gt) ==T in index order
        int gt_tot = 0, gt_run = 0, eq_run = 0;
#pragma unroll
        for (int j = 0; j < 17; ++j) {
            unsigned long long bg = __ballot(key[j] > T);
            unsigned long long be = __ballot(key[j] == T);
            gt_tot += (int)__popcll(bg);
            gt_run += prefix_cnt(bg);
            eq_run += prefix_cnt(be);
        }
        const int q = 515 - gt_tot;
        unsigned* Frow = F + w * 536;
#pragma unroll
        for (int j = 0; j < 17; ++j) {
            bool isgt = key[j] > T;
            bool iseq = key[j] == T;
            int pos = gt_run + (eq_run < q ? eq_run : q);
            if (isgt || (iseq && eq_run < q)) {
                float v = fast_tanh(fkey_inv(key[j]));
                unsigned h = f2bf_rne(v);
                float fh = __uint_as_float(h << 16);
                unsigned l = f2bf_rne(v - fh);
                Frow[4 + pos] = (h << 16) | l;
            }
            gt_run += isgt ? 1 : 0;
            eq_run += iseq ? 1 : 0;
        }
    }

    // A-fragment build (no F dependency -- before barrier so waves 12/13 overlap it
    // with phase B). k-slot (q,mm): row i = 3q + mm/5, tap t = mm%5 (mm=15 zero pad).
    const int jA = lane & 15;
    const int q3 = lane >> 4;
    short8 Ah0, Ah1, Al0, Al1;
    {
        float wt[16];
#pragma unroll
        for (int mm = 0; mm < 16; ++mm) {
            float v = 0.f;
            if (mm < 15 && jA < 14) {
                const int irow = 3 * q3 + mm / 5;          // mm/5, mm%5 compile-time
                const int t = mm % 5;
                const int h2 = (irow >= 6) ? 1 : 0;
                v = w2[(((2 * r2 + h2) * 14 + jA) * 6 + (irow - 6 * h2)) * 5 + t];
            }
            wt[mm] = v;
        }
#pragma unroll
        for (int m = 0; m < 8; ++m) {
            unsigned h0 = f2bf_rne(wt[m]);
            float fh0 = __uint_as_float(h0 << 16);
            Ah0[m] = (short)h0;
            Al0[m] = (short)f2bf_rne(wt[m] - fh0);
            unsigned h1 = f2bf_rne(wt[8 + m]);
            float fh1 = __uint_as_float(h1 << 16);
            Ah1[m] = (short)h1;
            Al1[m] = (short)f2bf_rne(wt[8 + m] - fh1);
        }
    }
    __syncthreads();

    // Phase C1: conv2+fold via split-precision MFMA. OUT[j][p] = sum_{k<60} A[j][k]*B[k][p]
    // B fragments rebuilt from packed u32 F with shift/or only (bit-identical to R11).
    // Lane map (verified vs stage3): A row / B col = lane&15; k-quad = lane>>4;
    // D: row = (lane>>4)*4 + r (= channel), col = lane&15 (= position).
    float* OUT = X;
    for (int tile = w; tile < 33; tile += 14) {            // 33 col-tiles over 14 waves
        const int p0 = tile << 4;
        const int bidx = (3 * q3) * 536 + p0 + jA;         // per-lane base; offsets imm
        unsigned u[16];
#pragma unroll
        for (int mm = 0; mm < 15; ++mm) u[mm] = F[bidx + (mm / 5) * 536 + (mm % 5)];
        u[15] = 0u;
        VPack bh0, bl0, bh1, bl1;
#pragma unroll
        for (int k = 0; k < 4; ++k) {
            unsigned a = u[2 * k], bq = u[2 * k + 1];
            bh0.i[k] = (int)((a >> 16) | (bq & 0xffff0000u));
            bl0.i[k] = (int)((a & 0xffffu) | (bq << 16));
            unsigned c = u[8 + 2 * k], d = u[9 + 2 * k];   // k=3 -> u[14], u[15]=0
            bh1.i[k] = (int)((c >> 16) | (d & 0xffff0000u));
            bl1.i[k] = (int)((c & 0xffffu) | (d << 16));
        }
        f32x4 d0 = {0.f, 0.f, 0.f, 0.f};
        d0 = __builtin_amdgcn_mfma_f32_16x16x32_bf16(Ah0, bh0.s, d0, 0, 0, 0);
        d0 = __builtin_amdgcn_mfma_f32_16x16x32_bf16(Ah1, bh1.s, d0, 0, 0, 0);
        d0 = __builtin_amdgcn_mfma_f32_16x16x32_bf16(Ah0, bl0.s, d0, 0, 0, 0);
        d0 = __builtin_amdgcn_mfma_f32_16x16x32_bf16(Ah1, bl1.s, d0, 0, 0, 0);
        d0 = __builtin_amdgcn_mfma_f32_16x16x32_bf16(Al0, bh0.s, d0, 0, 0, 0);
        d0 = __builtin_amdgcn_mfma_f32_16x16x32_bf16(Al1, bh1.s, d0, 0, 0, 0);
        float* orow = OUT + (q3 * 4) * 532 + p0 + jA;
#pragma unroll
        for (int r = 0; r < 4; ++r) orow[r * 532] = d0[r]; // rows 14,15 unused scratch
    }
    __syncthreads();

    // Phase C2: wave w = channel j: kmax4 over OUT[j][0..519) + bias + tanh -> H
    {
        const int j = w;
        const int base = lane * 9;                            // 9 outputs/lane, 576 >= 519
        const int bidx2 = __builtin_amdgcn_readfirstlane((2 * r2) * 14 + j);
        const float bias2 = b2[bidx2] + b2[bidx2 + 14];       // uniform shift: select-safe
        float vv[9];
#pragma unroll
        for (int jj = 0; jj < 9; ++jj)
            vv[jj] = (base + jj < 519) ? OUT[j * 532 + base + jj] : -INFINITY;
        float sv[4]; int si[4];
#pragma unroll
        for (int it = 0; it < 4; ++it) {
            float m = vv[0]; int mi = base;
#pragma unroll
            for (int jj = 1; jj < 9; ++jj) { if (vv[jj] > m) { m = vv[jj]; mi = base + jj; } }
#pragma unroll
            for (int d = 1; d < 64; d <<= 1) {
                float om = __shfl_xor(m, d, 64);
                int omi = __shfl_xor(mi, d, 64);
                if (om > m || (om == m && omi < mi)) { m = om; mi = omi; }
            }
            sv[it] = m; si[it] = mi;
            int lj = mi - base;
#pragma unroll
            for (int jj = 0; jj < 9; ++jj) if (jj == lj) vv[jj] = -INFINITY;
        }
#define CSWAP(a, bq) { if (si[a] > si[bq]) { int ti = si[a]; si[a] = si[bq]; si[bq] = ti; \
                                             float tv = sv[a]; sv[a] = sv[bq]; sv[bq] = tv; } }
        CSWAP(0, 1) CSWAP(2, 3) CSWAP(0, 2) CSWAP(1, 3) CSWAP(1, 2)
#undef CSWAP
        if (lane == 0) {
            __hip_bfloat16* op = H + (size_t)b * 3584 + (r2 * 14 + j) * 4;
#pragma unroll
            for (int k = 0; k < 4; ++k) op[k] = __float2bfloat16(fast_tanh(sv[k] + bias2));
        }
    }
}

// ---------------- Stage 3: (32x3584) @ wf^T (3584x1000) + bf via MFMA, full K per block ----
// grid = 63 col-tiles x 2 M-halves = 126 blocks, 512 thr (8 waves split K, LDS reduce).
// Writes out = acc + bf directly: no bias_init kernel, no atomics.
__global__ __launch_bounds__(512) void stage3_kernel(
    const __hip_bfloat16* __restrict__ Hb, const float* __restrict__ wf,
    const float* __restrict__ bfv, float* __restrict__ out)
{
    __shared__ __align__(16) float sred[8 * 256];
    const int nt = blockIdx.x % 63;
    const int mh = blockIdx.x / 63;                 // 0..1: rows mh*16..mh*16+15
    const int w = threadIdx.x >> 6, lane = threadIdx.x & 63;
    const int row = lane & 15, quad = lane >> 4;
    const int c = nt * 16 + row;
    const bool cvalid = (c < 1000);
    const int kofs = w * 448 + quad * 8;
    const __hip_bfloat16* ap = Hb + (size_t)(mh * 16 + row) * 3584 + kofs;
    const float* bp = wf + (size_t)(cvalid ? c : 0) * 3584 + kofs;

    f32x4 acc = {0.f, 0.f, 0.f, 0.f};
#pragma unroll
    for (int it = 0; it < 14; ++it) {
        short8 a0 = *(const short8*)(ap + it * 32);
        float4 p0 = *(const float4*)(bp + it * 32);
        float4 p1 = *(const float4*)(bp + it * 32 + 4);
        short8 bfr;
        bfr[0] = (short)f2bf_rne(p0.x); bfr[1] = (short)f2bf_rne(p0.y);
        bfr[2] = (short)f2bf_rne(p0.z); bfr[3] = (short)f2bf_rne(p0.w);
        bfr[4] = (short)f2bf_rne(p1.x); bfr[5] = (short)f2bf_rne(p1.y);
        bfr[6] = (short)f2bf_rne(p1.z); bfr[7] = (short)f2bf_rne(p1.w);
        if (!cvalid) bfr = short8{0, 0, 0, 0, 0, 0, 0, 0};
        acc = __builtin_amdgcn_mfma_f32_16x16x32_bf16(a0, bfr, acc, 0, 0, 0);
    }
#pragma unroll
    for (int r_ = 0; r_ < 4; ++r_) sred[w * 256 + lane * 4 + r_] = acc[r_];
    __syncthreads();
    if (threadIdx.x < 64) {
        const int l2 = threadIdx.x;
        const int rr = l2 & 15, qq = l2 >> 4;
        const int cc = nt * 16 + rr;
        if (cc < 1000) {
            const float bias = bfv[cc];
#pragma unroll
            for (int r_ = 0; r_ < 4; ++r_) {
                float s = 0.f;
#pragma unroll
                for (int ww = 0; ww < 8; ++ww) s += sred[ww * 256 + l2 * 4 + r_];
                int brow = mh * 16 + qq * 4 + r_;
                out[brow * 1000 + cc] = s + bias;
            }
        }
    }
}

extern "C" void kernel_launch(void* const* d_in, const int* in_sizes, int n_in,
                              void* d_out, int out_size, void* d_ws, size_t ws_size,
                              hipStream_t stream) {
    const int* x      = (const int*)d_in[0];
    const float* emb  = (const float*)d_in[1];
    const float* w1   = (const float*)d_in[2];
    const float* b1   = (const float*)d_in[3];
    const float* w2   = (const float*)d_in[4];
    const float* b2   = (const float*)d_in[5];
    const float* wf   = (const float*)d_in[6];
    const float* bfv  = (const float*)d_in[7];

    __hip_bfloat16* H = (__hip_bfloat16*)d_ws;      // 32*3584*2 = 229,376 B

    stage12_kernel<<<32 * 64, 896, 0, stream>>>(x, emb, w1, b1, w2, b2, H);
    stage3_kernel<<<126, 512, 0, stream>>>(H, wf, bfv, (float*)d_out);
}

// Round 6
// 243.961 us; speedup vs baseline: 1.1202x; 1.0109x over previous
//
#include <hip/hip_runtime.h>
#include <hip/hip_bf16.h>

// Shapes: B=32 S=1024 D=256 V=50257 C=1000   (float tensors fp32; x int32; out fp32)
// conv1: groups=256, Cin/g=1, Cout/g=6, K=7, pad=6 -> L1=1030; fold -> 768 ch
// kmax k1=515 -> tanh -> conv2: groups=128, Cin/g=6, Cout/g=14, K=5, pad=4 -> L2=519
// fold -> 896 ch -> kmax 4 -> tanh -> (32,3584) @ wf^T(1000,3584) + bf
//
// R13 = R12 (152us stage12) + (1) packed-fp32 conv1: f32x2 {ch0,ch1} accumulators ->
// v_pk_fma_f32 (gfx950's 157TF fp32 = 2x packed rate), 14 scalar FMA -> 7 pk_fma + 1
// add per output; (2) F zero-fill only the 21 pad entries/row (compaction writes a
// bijection onto [4,519)); (3) wave-uniform w1/b1/b2 scalar loads hoisted above the
// phase-A barrier (SMEM latency hides under gather); (4) C1 MFMA chain split into 2
// accumulators + s_setprio(1) around the cluster.

typedef __attribute__((ext_vector_type(8))) short short8;
typedef __attribute__((ext_vector_type(4))) float f32x4;
typedef __attribute__((ext_vector_type(2))) float f32x2;
typedef __attribute__((ext_vector_type(4))) int int4v;

union VPack { int4v i; short8 s; };

__device__ __forceinline__ float fast_tanh(float x) {
    float e = __expf(2.f * x);          // tanh = 1 - 2/(e^{2x}+1); saturates at +-inf
    return 1.f - 2.f / (e + 1.f);
}

__device__ __forceinline__ unsigned fkey(float f) {
    unsigned u = __float_as_uint(f);
    return (u & 0x80000000u) ? ~u : (u | 0x80000000u);   // monotone order-preserving key
}

__device__ __forceinline__ float fkey_inv(unsigned k) {
    unsigned u = (k & 0x80000000u) ? (k ^ 0x80000000u) : ~k;
    return __uint_as_float(u);
}

__device__ __forceinline__ unsigned f2bf_rne(float f) {
    unsigned u = __float_as_uint(f);
    return (u + 0x7fffu + ((u >> 16) & 1u)) >> 16;
}

// popcount of mask restricted to lanes below this lane (HW prefix-popcount)
__device__ __forceinline__ int prefix_cnt(unsigned long long m) {
    return (int)__builtin_amdgcn_mbcnt_hi((unsigned)(m >> 32),
                 __builtin_amdgcn_mbcnt_lo((unsigned)m, 0u));
}

// ---------------- Fused: gather + conv1 + fold + kmax(515) + tanh + conv2(MFMA) + fold + kmax(4) + tanh ----
// grid = 32*64 blocks (b, r2) after swizzle, 896 threads = 14 waves.
__global__ __launch_bounds__(896) void stage12_kernel(
    const int* __restrict__ x, const float* __restrict__ emb,
    const float* __restrict__ w1, const float* __restrict__ b1,
    const float* __restrict__ w2, const float* __restrict__ b2,
    __hip_bfloat16* __restrict__ H)
{
    // Region X: e[4*1104] f32 during phases A/B; OUT[16][532] f32 during phase C.
    __shared__ __align__(16) float X[8512];
    __shared__ __align__(16) unsigned F[12 * 536];  // bf16 hi<<16 | lo, [4+pos], pos<515
    const int hw = blockIdx.x;
    const int logical = ((hw & 7) << 8) | (hw >> 3);   // XCD k -> b in [4k,4k+4), all r2
    const int b = logical >> 6;
    const int r2 = logical & 63;
    const int tid = threadIdx.x;
    const int w = tid >> 6;
    const int lane = tid & 63;
    float* e = X;

    // Hoisted wave-uniform scalar loads (SGPR; latency hides under phase-A gather).
    const int half = (w >= 6) ? 1 : 0;
    const int c0 = __builtin_amdgcn_readfirstlane(
        (2 * (2 * r2 + half)) * 6 + ((w < 12) ? (w - half * 6) : 0));
    const int c1 = c0 + 6;
    float wA[7], wB[7];
#pragma unroll
    for (int t = 0; t < 7; ++t) { wA[t] = w1[c0 * 7 + t]; wB[t] = w1[c1 * 7 + t]; }
    const float bias = b1[c0] + b1[c1];
    const int bidx2 = __builtin_amdgcn_readfirstlane((2 * r2) * 14 + w);
    const float bias2 = b2[bidx2] + b2[bidx2 + 14];       // C2 bias (uniform shift)

    // Phase A: direct gather. Issue both x loads, then both scattered 16B emb loads,
    // zero only F's pad entries (front 4 + tail 17 per row), commit to LDS planes.
    {
        const int l0 = tid - 6;
        const int l1 = tid + 890;                   // (tid+896) - 6
        int t0 = -1, t1 = -1;
        if (l0 >= 0 && l0 < 1024) t0 = x[(b << 10) + l0];
        if (tid < 208 && l1 < 1024) t1 = x[(b << 10) + l1];
        float4 v0 = {0.f, 0.f, 0.f, 0.f}, v1 = {0.f, 0.f, 0.f, 0.f};
        if (t0 >= 0) v0 = *(const float4*)(emb + ((size_t)t0 << 8) + (r2 << 2));
        if (t1 >= 0) v1 = *(const float4*)(emb + ((size_t)t1 << 8) + (r2 << 2));
        if (tid < 252) {                             // 12 rows x 21 pad entries
            int row = tid / 21, k = tid - row * 21;
            F[row * 536 + (k < 4 ? k : 515 + k)] = 0u;
        }
        e[0 * 1104 + tid] = v0.x; e[1 * 1104 + tid] = v0.y;
        e[2 * 1104 + tid] = v0.z; e[3 * 1104 + tid] = v0.w;
        if (tid < 208) {
            const int idx = tid + 896;
            e[0 * 1104 + idx] = v1.x; e[1 * 1104 + idx] = v1.y;
            e[2 * 1104 + idx] = v1.z; e[3 * 1104 + idx] = v1.w;
        }
    }
    __syncthreads();

    // Phase B: waves 0..11 -> folded conv1 row i=w (packed-fp32 FMA), exact
    // radix-select 515, tanh, split to bf16 hi/lo, pack -> F (u32)
    if (w < 12) {
        const float* ep0 = e + (2 * half) * 1104;     // emb ch 4*r2 + 2*half
        const float* ep1 = ep0 + 1104;
        f32x2 wv[7];
#pragma unroll
        for (int t = 0; t < 7; ++t) wv[t] = f32x2{wA[t], wB[t]};

        const int pos0 = lane * 17;                   // 17 contiguous outputs/lane
        f32x2 win[7];                                 // rolling window {ch0,ch1}
#pragma unroll
        for (int t = 0; t < 7; ++t) win[t] = f32x2{ep0[pos0 + t], ep1[pos0 + t]};

        unsigned key[17];
#pragma unroll
        for (int j = 0; j < 17; ++j) {
            f32x2 acc = f32x2{bias, 0.f};
#pragma unroll
            for (int t = 0; t < 7; ++t) acc += win[t] * wv[t];   // v_pk_fma_f32
            float a = acc.x + acc.y;
            key[j] = (pos0 + j < 1030) ? fkey(a) : 0u;    // pads below any real key
            if (j < 16) {
#pragma unroll
                for (int t = 0; t < 6; ++t) win[t] = win[t + 1];
                win[6] = f32x2{ep0[pos0 + j + 7], ep1[pos0 + j + 7]};
            }
        }

        // exact radix-select of 515th-largest key; early exit when the set separates
        unsigned T = 0u;
        for (int bit = 31; bit >= 0; --bit) {
            unsigned cand = T | (1u << bit);
            int cnt = 0;
#pragma unroll
            for (int j = 0; j < 17; ++j) cnt += (int)__popcll(__ballot(key[j] >= cand));
            if (cnt >= 515) T = cand;
            if (cnt == 515) break;
        }

        // order-preserving compaction: all >T plus first (515-#gt) ==T in index order
        int gt_tot = 0, gt_run = 0, eq_run = 0;
#pragma unroll
        for (int j = 0; j < 17; ++j) {
            unsigned long long bg = __ballot(key[j] > T);
            unsigned long long be = __ballot(key[j] == T);
            gt_tot += (int)__popcll(bg);
            gt_run += prefix_cnt(bg);
            eq_run += prefix_cnt(be);
        }
        const int q = 515 - gt_tot;
        unsigned* Frow = F + w * 536;
#pragma unroll
        for (int j = 0; j < 17; ++j) {
            bool isgt = key[j] > T;
            bool iseq = key[j] == T;
            int pos = gt_run + (eq_run < q ? eq_run : q);
            if (isgt || (iseq && eq_run < q)) {
                float v = fast_tanh(fkey_inv(key[j]));
                unsigned h = f2bf_rne(v);
                float fh = __uint_as_float(h << 16);
                unsigned l = f2bf_rne(v - fh);
                Frow[4 + pos] = (h << 16) | l;
            }
            gt_run += isgt ? 1 : 0;
            eq_run += iseq ? 1 : 0;
        }
    }

    // A-fragment build (no F dependency -- before barrier so waves 12/13 overlap it
    // with phase B). k-slot (q,mm): row i = 3q + mm/5, tap t = mm%5 (mm=15 zero pad).
    const int jA = lane & 15;
    const int q3 = lane >> 4;
    short8 Ah0, Ah1, Al0, Al1;
    {
        float wt[16];
#pragma unroll
        for (int mm = 0; mm < 16; ++mm) {
            float v = 0.f;
            if (mm < 15 && jA < 14) {
                const int irow = 3 * q3 + mm / 5;          // mm/5, mm%5 compile-time
                const int t = mm % 5;
                const int h2 = (irow >= 6) ? 1 : 0;
                v = w2[(((2 * r2 + h2) * 14 + jA) * 6 + (irow - 6 * h2)) * 5 + t];
            }
            wt[mm] = v;
        }
#pragma unroll
        for (int m = 0; m < 8; ++m) {
            unsigned h0 = f2bf_rne(wt[m]);
            float fh0 = __uint_as_float(h0 << 16);
            Ah0[m] = (short)h0;
            Al0[m] = (short)f2bf_rne(wt[m] - fh0);
            unsigned h1 = f2bf_rne(wt[8 + m]);
            float fh1 = __uint_as_float(h1 << 16);
            Ah1[m] = (short)h1;
            Al1[m] = (short)f2bf_rne(wt[8 + m] - fh1);
        }
    }
    __syncthreads();

    // Phase C1: conv2+fold via split-precision MFMA. OUT[j][p] = sum_{k<60} A[j][k]*B[k][p]
    // B fragments rebuilt from packed u32 F with shift/or only (bit-identical math).
    // Lane map (verified vs stage3): A row / B col = lane&15; k-quad = lane>>4;
    // D: row = (lane>>4)*4 + r (= channel), col = lane&15 (= position).
    float* OUT = X;
    for (int tile = w; tile < 33; tile += 14) {            // 33 col-tiles over 14 waves
        const int p0 = tile << 4;
        const int bidx = (3 * q3) * 536 + p0 + jA;         // per-lane base; offsets imm
        unsigned u[16];
#pragma unroll
        for (int mm = 0; mm < 15; ++mm) u[mm] = F[bidx + (mm / 5) * 536 + (mm % 5)];
        u[15] = 0u;
        VPack bh0, bl0, bh1, bl1;
#pragma unroll
        for (int k = 0; k < 4; ++k) {
            unsigned a = u[2 * k], bq = u[2 * k + 1];
            bh0.i[k] = (int)((a >> 16) | (bq & 0xffff0000u));
            bl0.i[k] = (int)((a & 0xffffu) | (bq << 16));
            unsigned c = u[8 + 2 * k], d = u[9 + 2 * k];   // k=3 -> u[14], u[15]=0
            bh1.i[k] = (int)((c >> 16) | (d & 0xffff0000u));
            bl1.i[k] = (int)((c & 0xffffu) | (d << 16));
        }
        __builtin_amdgcn_s_setprio(1);
        f32x4 d0 = {0.f, 0.f, 0.f, 0.f};
        f32x4 d1 = {0.f, 0.f, 0.f, 0.f};
        d0 = __builtin_amdgcn_mfma_f32_16x16x32_bf16(Ah0, bh0.s, d0, 0, 0, 0);
        d1 = __builtin_amdgcn_mfma_f32_16x16x32_bf16(Ah1, bh1.s, d1, 0, 0, 0);
        d0 = __builtin_amdgcn_mfma_f32_16x16x32_bf16(Ah0, bl0.s, d0, 0, 0, 0);
        d1 = __builtin_amdgcn_mfma_f32_16x16x32_bf16(Ah1, bl1.s, d1, 0, 0, 0);
        d0 = __builtin_amdgcn_mfma_f32_16x16x32_bf16(Al0, bh0.s, d0, 0, 0, 0);
        d1 = __builtin_amdgcn_mfma_f32_16x16x32_bf16(Al1, bh1.s, d1, 0, 0, 0);
        __builtin_amdgcn_s_setprio(0);
        float* orow = OUT + (q3 * 4) * 532 + p0 + jA;
#pragma unroll
        for (int r = 0; r < 4; ++r) orow[r * 532] = d0[r] + d1[r]; // rows 14,15 scratch
    }
    __syncthreads();

    // Phase C2: wave w = channel j: kmax4 over OUT[j][0..519) + bias + tanh -> H
    {
        const int j = w;
        const int base = lane * 9;                            // 9 outputs/lane, 576 >= 519
        float vv[9];
#pragma unroll
        for (int jj = 0; jj < 9; ++jj)
            vv[jj] = (base + jj < 519) ? OUT[j * 532 + base + jj] : -INFINITY;
        float sv[4]; int si[4];
#pragma unroll
        for (int it = 0; it < 4; ++it) {
            float m = vv[0]; int mi = base;
#pragma unroll
            for (int jj = 1; jj < 9; ++jj) { if (vv[jj] > m) { m = vv[jj]; mi = base + jj; } }
#pragma unroll
            for (int d = 1; d < 64; d <<= 1) {
                float om = __shfl_xor(m, d, 64);
                int omi = __shfl_xor(mi, d, 64);
                if (om > m || (om == m && omi < mi)) { m = om; mi = omi; }
            }
            sv[it] = m; si[it] = mi;
            int lj = mi - base;
#pragma unroll
            for (int jj = 0; jj < 9; ++jj) if (jj == lj) vv[jj] = -INFINITY;
        }
#define CSWAP(a, bq) { if (si[a] > si[bq]) { int ti = si[a]; si[a] = si[bq]; si[bq] = ti; \
                                             float tv = sv[a]; sv[a] = sv[bq]; sv[bq] = tv; } }
        CSWAP(0, 1) CSWAP(2, 3) CSWAP(0, 2) CSWAP(1, 3) CSWAP(1, 2)
#undef CSWAP
        if (lane == 0) {
            __hip_bfloat16* op = H + (size_t)b * 3584 + (r2 * 14 + j) * 4;
#pragma unroll
            for (int k = 0; k < 4; ++k) op[k] = __float2bfloat16(fast_tanh(sv[k] + bias2));
        }
    }
}

// ---------------- Stage 3: (32x3584) @ wf^T (3584x1000) + bf via MFMA, full K per block ----
// grid = 63 col-tiles x 2 M-halves = 126 blocks, 512 thr (8 waves split K, LDS reduce).
// Writes out = acc + bf directly: no bias_init kernel, no atomics.
__global__ __launch_bounds__(512) void stage3_kernel(
    const __hip_bfloat16* __restrict__ Hb, const float* __restrict__ wf,
    const float* __restrict__ bfv, float* __restrict__ out)
{
    __shared__ __align__(16) float sred[8 * 256];
    const int nt = blockIdx.x % 63;
    const int mh = blockIdx.x / 63;                 // 0..1: rows mh*16..mh*16+15
    const int w = threadIdx.x >> 6, lane = threadIdx.x & 63;
    const int row = lane & 15, quad = lane >> 4;
    const int c = nt * 16 + row;
    const bool cvalid = (c < 1000);
    const int kofs = w * 448 + quad * 8;
    const __hip_bfloat16* ap = Hb + (size_t)(mh * 16 + row) * 3584 + kofs;
    const float* bp = wf + (size_t)(cvalid ? c : 0) * 3584 + kofs;

    f32x4 acc = {0.f, 0.f, 0.f, 0.f};
#pragma unroll
    for (int it = 0; it < 14; ++it) {
        short8 a0 = *(const short8*)(ap + it * 32);
        float4 p0 = *(const float4*)(bp + it * 32);
        float4 p1 = *(const float4*)(bp + it * 32 + 4);
        short8 bfr;
        bfr[0] = (short)f2bf_rne(p0.x); bfr[1] = (short)f2bf_rne(p0.y);
        bfr[2] = (short)f2bf_rne(p0.z); bfr[3] = (short)f2bf_rne(p0.w);
        bfr[4] = (short)f2bf_rne(p1.x); bfr[5] = (short)f2bf_rne(p1.y);
        bfr[6] = (short)f2bf_rne(p1.z); bfr[7] = (short)f2bf_rne(p1.w);
        if (!cvalid) bfr = short8{0, 0, 0, 0, 0, 0, 0, 0};
        acc = __builtin_amdgcn_mfma_f32_16x16x32_bf16(a0, bfr, acc, 0, 0, 0);
    }
#pragma unroll
    for (int r_ = 0; r_ < 4; ++r_) sred[w * 256 + lane * 4 + r_] = acc[r_];
    __syncthreads();
    if (threadIdx.x < 64) {
        const int l2 = threadIdx.x;
        const int rr = l2 & 15, qq = l2 >> 4;
        const int cc = nt * 16 + rr;
        if (cc < 1000) {
            const float bias = bfv[cc];
#pragma unroll
            for (int r_ = 0; r_ < 4; ++r_) {
                float s = 0.f;
#pragma unroll
                for (int ww = 0; ww < 8; ++ww) s += sred[ww * 256 + l2 * 4 + r_];
                int brow = mh * 16 + qq * 4 + r_;
                out[brow * 1000 + cc] = s + bias;
            }
        }
    }
}

extern "C" void kernel_launch(void* const* d_in, const int* in_sizes, int n_in,
                              void* d_out, int out_size, void* d_ws, size_t ws_size,
                              hipStream_t stream) {
    const int* x      = (const int*)d_in[0];
    const float* emb  = (const float*)d_in[1];
    const float* w1   = (const float*)d_in[2];
    const float* b1   = (const float*)d_in[3];
    const float* w2   = (const float*)d_in[4];
    const float* b2   = (const float*)d_in[5];
    const float* wf   = (const float*)d_in[6];
    const float* bfv  = (const float*)d_in[7];

    __hip_bfloat16* H = (__hip_bfloat16*)d_ws;      // 32*3584*2 = 229,376 B

    stage12_kernel<<<32 * 64, 896, 0, stream>>>(x, emb, w1, b1, w2, b2, H);
    stage3_kernel<<<126, 512, 0, stream>>>(H, wf, bfv, (float*)d_out);
}

// Round 7
// 243.401 us; speedup vs baseline: 1.1228x; 1.0023x over previous
//
#include <hip/hip_runtime.h>
#include <hip/hip_bf16.h>

// Shapes: B=32 S=1024 D=256 V=50257 C=1000   (float tensors fp32; x int32; out fp32)
// conv1: groups=256, Cin/g=1, Cout/g=6, K=7, pad=6 -> L1=1030; fold -> 768 ch
// kmax k1=515 -> tanh -> conv2: groups=128, Cin/g=6, Cout/g=14, K=5, pad=4 -> L2=519
// fold -> 896 ch -> kmax 4 -> tanh -> (32,3584) @ wf^T(1000,3584) + bf
//
// R14 = R13 post-mortem decomposition. R13 bundled 4 changes and stage12 regressed
// 152->166us (VALUBusy 62.8->56.4% at LONGER duration = added stalls, not fewer
// instructions). Reverted here: (a) s_setprio around C1 MFMAs (hurts lockstep
// barrier phases -- all 14 waves enter C1 together; prio-boosted MFMA waves starve
// the VALU fragment builds they depend on); (b) pad-only F zero-fill (the full
// 6432-word zero loop was phase A's gather-latency hider). Kept from R13 (neutral or
// positive): packed-fp32 conv1 (v_pk_fma_f32), hoisted wave-uniform w1/b1/b2 scalar
// loads, C1 dual-accumulator split, 512-thread stage3.

typedef __attribute__((ext_vector_type(8))) short short8;
typedef __attribute__((ext_vector_type(4))) float f32x4;
typedef __attribute__((ext_vector_type(2))) float f32x2;
typedef __attribute__((ext_vector_type(4))) int int4v;

union VPack { int4v i; short8 s; };

__device__ __forceinline__ float fast_tanh(float x) {
    float e = __expf(2.f * x);          // tanh = 1 - 2/(e^{2x}+1); saturates at +-inf
    return 1.f - 2.f / (e + 1.f);
}

__device__ __forceinline__ unsigned fkey(float f) {
    unsigned u = __float_as_uint(f);
    return (u & 0x80000000u) ? ~u : (u | 0x80000000u);   // monotone order-preserving key
}

__device__ __forceinline__ float fkey_inv(unsigned k) {
    unsigned u = (k & 0x80000000u) ? (k ^ 0x80000000u) : ~k;
    return __uint_as_float(u);
}

__device__ __forceinline__ unsigned f2bf_rne(float f) {
    unsigned u = __float_as_uint(f);
    return (u + 0x7fffu + ((u >> 16) & 1u)) >> 16;
}

// popcount of mask restricted to lanes below this lane (HW prefix-popcount)
__device__ __forceinline__ int prefix_cnt(unsigned long long m) {
    return (int)__builtin_amdgcn_mbcnt_hi((unsigned)(m >> 32),
                 __builtin_amdgcn_mbcnt_lo((unsigned)m, 0u));
}

// ---------------- Fused: gather + conv1 + fold + kmax(515) + tanh + conv2(MFMA) + fold + kmax(4) + tanh ----
// grid = 32*64 blocks (b, r2) after swizzle, 896 threads = 14 waves.
__global__ __launch_bounds__(896) void stage12_kernel(
    const int* __restrict__ x, const float* __restrict__ emb,
    const float* __restrict__ w1, const float* __restrict__ b1,
    const float* __restrict__ w2, const float* __restrict__ b2,
    __hip_bfloat16* __restrict__ H)
{
    // Region X: e[4*1104] f32 during phases A/B; OUT[16][532] f32 during phase C.
    __shared__ __align__(16) float X[8512];
    __shared__ __align__(16) unsigned F[12 * 536];  // bf16 hi<<16 | lo, [4+pos], pos<515
    const int hw = blockIdx.x;
    const int logical = ((hw & 7) << 8) | (hw >> 3);   // XCD k -> b in [4k,4k+4), all r2
    const int b = logical >> 6;
    const int r2 = logical & 63;
    const int tid = threadIdx.x;
    const int w = tid >> 6;
    const int lane = tid & 63;
    float* e = X;

    // Hoisted wave-uniform scalar loads (SGPR; latency hides under phase-A gather).
    const int half = (w >= 6) ? 1 : 0;
    const int c0 = __builtin_amdgcn_readfirstlane(
        (2 * (2 * r2 + half)) * 6 + ((w < 12) ? (w - half * 6) : 0));
    const int c1 = c0 + 6;
    float wA[7], wB[7];
#pragma unroll
    for (int t = 0; t < 7; ++t) { wA[t] = w1[c0 * 7 + t]; wB[t] = w1[c1 * 7 + t]; }
    const float bias = b1[c0] + b1[c1];
    const int bidx2 = __builtin_amdgcn_readfirstlane((2 * r2) * 14 + w);
    const float bias2 = b2[bidx2] + b2[bidx2 + 14];       // C2 bias (uniform shift)

    // Phase A: direct gather. Issue both x loads, then both scattered 16B emb loads;
    // full F zero-fill overlaps the load latency; then commit to LDS planes.
    {
        const int l0 = tid - 6;
        const int l1 = tid + 890;                   // (tid+896) - 6
        int t0 = -1, t1 = -1;
        if (l0 >= 0 && l0 < 1024) t0 = x[(b << 10) + l0];
        if (tid < 208 && l1 < 1024) t1 = x[(b << 10) + l1];
        float4 v0 = {0.f, 0.f, 0.f, 0.f}, v1 = {0.f, 0.f, 0.f, 0.f};
        if (t0 >= 0) v0 = *(const float4*)(emb + ((size_t)t0 << 8) + (r2 << 2));
        if (t1 >= 0) v1 = *(const float4*)(emb + ((size_t)t1 << 8) + (r2 << 2));
        for (int i = tid; i < 12 * 536; i += 896) F[i] = 0u;
        e[0 * 1104 + tid] = v0.x; e[1 * 1104 + tid] = v0.y;
        e[2 * 1104 + tid] = v0.z; e[3 * 1104 + tid] = v0.w;
        if (tid < 208) {
            const int idx = tid + 896;
            e[0 * 1104 + idx] = v1.x; e[1 * 1104 + idx] = v1.y;
            e[2 * 1104 + idx] = v1.z; e[3 * 1104 + idx] = v1.w;
        }
    }
    __syncthreads();

    // Phase B: waves 0..11 -> folded conv1 row i=w (packed-fp32 FMA), exact
    // radix-select 515, tanh, split to bf16 hi/lo, pack -> F (u32)
    if (w < 12) {
        const float* ep0 = e + (2 * half) * 1104;     // emb ch 4*r2 + 2*half
        const float* ep1 = ep0 + 1104;
        f32x2 wv[7];
#pragma unroll
        for (int t = 0; t < 7; ++t) wv[t] = f32x2{wA[t], wB[t]};

        const int pos0 = lane * 17;                   // 17 contiguous outputs/lane
        f32x2 win[7];                                 // rolling window {ch0,ch1}
#pragma unroll
        for (int t = 0; t < 7; ++t) win[t] = f32x2{ep0[pos0 + t], ep1[pos0 + t]};

        unsigned key[17];
#pragma unroll
        for (int j = 0; j < 17; ++j) {
            f32x2 acc = f32x2{bias, 0.f};
#pragma unroll
            for (int t = 0; t < 7; ++t) acc += win[t] * wv[t];   // v_pk_fma_f32
            float a = acc.x + acc.y;
            key[j] = (pos0 + j < 1030) ? fkey(a) : 0u;    // pads below any real key
            if (j < 16) {
#pragma unroll
                for (int t = 0; t < 6; ++t) win[t] = win[t + 1];
                win[6] = f32x2{ep0[pos0 + j + 7], ep1[pos0 + j + 7]};
            }
        }

        // exact radix-select of 515th-largest key; early exit when the set separates
        unsigned T = 0u;
        for (int bit = 31; bit >= 0; --bit) {
            unsigned cand = T | (1u << bit);
            int cnt = 0;
#pragma unroll
            for (int j = 0; j < 17; ++j) cnt += (int)__popcll(__ballot(key[j] >= cand));
            if (cnt >= 515) T = cand;
            if (cnt == 515) break;
        }

        // order-preserving compaction: all >T plus first (515-#gt) ==T in index order
        int gt_tot = 0, gt_run = 0, eq_run = 0;
#pragma unroll
        for (int j = 0; j < 17; ++j) {
            unsigned long long bg = __ballot(key[j] > T);
            unsigned long long be = __ballot(key[j] == T);
            gt_tot += (int)__popcll(bg);
            gt_run += prefix_cnt(bg);
            eq_run += prefix_cnt(be);
        }
        const int q = 515 - gt_tot;
        unsigned* Frow = F + w * 536;
#pragma unroll
        for (int j = 0; j < 17; ++j) {
            bool isgt = key[j] > T;
            bool iseq = key[j] == T;
            int pos = gt_run + (eq_run < q ? eq_run : q);
            if (isgt || (iseq && eq_run < q)) {
                float v = fast_tanh(fkey_inv(key[j]));
                unsigned h = f2bf_rne(v);
                float fh = __uint_as_float(h << 16);
                unsigned l = f2bf_rne(v - fh);
                Frow[4 + pos] = (h << 16) | l;
            }
            gt_run += isgt ? 1 : 0;
            eq_run += iseq ? 1 : 0;
        }
    }

    // A-fragment build (no F dependency -- before barrier so waves 12/13 overlap it
    // with phase B). k-slot (q,mm): row i = 3q + mm/5, tap t = mm%5 (mm=15 zero pad).
    const int jA = lane & 15;
    const int q3 = lane >> 4;
    short8 Ah0, Ah1, Al0, Al1;
    {
        float wt[16];
#pragma unroll
        for (int mm = 0; mm < 16; ++mm) {
            float v = 0.f;
            if (mm < 15 && jA < 14) {
                const int irow = 3 * q3 + mm / 5;          // mm/5, mm%5 compile-time
                const int t = mm % 5;
                const int h2 = (irow >= 6) ? 1 : 0;
                v = w2[(((2 * r2 + h2) * 14 + jA) * 6 + (irow - 6 * h2)) * 5 + t];
            }
            wt[mm] = v;
        }
#pragma unroll
        for (int m = 0; m < 8; ++m) {
            unsigned h0 = f2bf_rne(wt[m]);
            float fh0 = __uint_as_float(h0 << 16);
            Ah0[m] = (short)h0;
            Al0[m] = (short)f2bf_rne(wt[m] - fh0);
            unsigned h1 = f2bf_rne(wt[8 + m]);
            float fh1 = __uint_as_float(h1 << 16);
            Ah1[m] = (short)h1;
            Al1[m] = (short)f2bf_rne(wt[8 + m] - fh1);
        }
    }
    __syncthreads();

    // Phase C1: conv2+fold via split-precision MFMA. OUT[j][p] = sum_{k<60} A[j][k]*B[k][p]
    // B fragments rebuilt from packed u32 F with shift/or only (bit-identical math).
    // Lane map (verified vs stage3): A row / B col = lane&15; k-quad = lane>>4;
    // D: row = (lane>>4)*4 + r (= channel), col = lane&15 (= position).
    float* OUT = X;
    for (int tile = w; tile < 33; tile += 14) {            // 33 col-tiles over 14 waves
        const int p0 = tile << 4;
        const int bidx = (3 * q3) * 536 + p0 + jA;         // per-lane base; offsets imm
        unsigned u[16];
#pragma unroll
        for (int mm = 0; mm < 15; ++mm) u[mm] = F[bidx + (mm / 5) * 536 + (mm % 5)];
        u[15] = 0u;
        VPack bh0, bl0, bh1, bl1;
#pragma unroll
        for (int k = 0; k < 4; ++k) {
            unsigned a = u[2 * k], bq = u[2 * k + 1];
            bh0.i[k] = (int)((a >> 16) | (bq & 0xffff0000u));
            bl0.i[k] = (int)((a & 0xffffu) | (bq << 16));
            unsigned c = u[8 + 2 * k], d = u[9 + 2 * k];   // k=3 -> u[14], u[15]=0
            bh1.i[k] = (int)((c >> 16) | (d & 0xffff0000u));
            bl1.i[k] = (int)((c & 0xffffu) | (d << 16));
        }
        f32x4 d0 = {0.f, 0.f, 0.f, 0.f};
        f32x4 d1 = {0.f, 0.f, 0.f, 0.f};
        d0 = __builtin_amdgcn_mfma_f32_16x16x32_bf16(Ah0, bh0.s, d0, 0, 0, 0);
        d1 = __builtin_amdgcn_mfma_f32_16x16x32_bf16(Ah1, bh1.s, d1, 0, 0, 0);
        d0 = __builtin_amdgcn_mfma_f32_16x16x32_bf16(Ah0, bl0.s, d0, 0, 0, 0);
        d1 = __builtin_amdgcn_mfma_f32_16x16x32_bf16(Ah1, bl1.s, d1, 0, 0, 0);
        d0 = __builtin_amdgcn_mfma_f32_16x16x32_bf16(Al0, bh0.s, d0, 0, 0, 0);
        d1 = __builtin_amdgcn_mfma_f32_16x16x32_bf16(Al1, bh1.s, d1, 0, 0, 0);
        float* orow = OUT + (q3 * 4) * 532 + p0 + jA;
#pragma unroll
        for (int r = 0; r < 4; ++r) orow[r * 532] = d0[r] + d1[r]; // rows 14,15 scratch
    }
    __syncthreads();

    // Phase C2: wave w = channel j: kmax4 over OUT[j][0..519) + bias + tanh -> H
    {
        const int j = w;
        const int base = lane * 9;                            // 9 outputs/lane, 576 >= 519
        float vv[9];
#pragma unroll
        for (int jj = 0; jj < 9; ++jj)
            vv[jj] = (base + jj < 519) ? OUT[j * 532 + base + jj] : -INFINITY;
        float sv[4]; int si[4];
#pragma unroll
        for (int it = 0; it < 4; ++it) {
            float m = vv[0]; int mi = base;
#pragma unroll
            for (int jj = 1; jj < 9; ++jj) { if (vv[jj] > m) { m = vv[jj]; mi = base + jj; } }
#pragma unroll
            for (int d = 1; d < 64; d <<= 1) {
                float om = __shfl_xor(m, d, 64);
                int omi = __shfl_xor(mi, d, 64);
                if (om > m || (om == m && omi < mi)) { m = om; mi = omi; }
            }
            sv[it] = m; si[it] = mi;
            int lj = mi - base;
#pragma unroll
            for (int jj = 0; jj < 9; ++jj) if (jj == lj) vv[jj] = -INFINITY;
        }
#define CSWAP(a, bq) { if (si[a] > si[bq]) { int ti = si[a]; si[a] = si[bq]; si[bq] = ti; \
                                             float tv = sv[a]; sv[a] = sv[bq]; sv[bq] = tv; } }
        CSWAP(0, 1) CSWAP(2, 3) CSWAP(0, 2) CSWAP(1, 3) CSWAP(1, 2)
#undef CSWAP
        if (lane == 0) {
            __hip_bfloat16* op = H + (size_t)b * 3584 + (r2 * 14 + j) * 4;
#pragma unroll
            for (int k = 0; k < 4; ++k) op[k] = __float2bfloat16(fast_tanh(sv[k] + bias2));
        }
    }
}

// ---------------- Stage 3: (32x3584) @ wf^T (3584x1000) + bf via MFMA, full K per block ----
// grid = 63 col-tiles x 2 M-halves = 126 blocks, 512 thr (8 waves split K, LDS reduce).
// Writes out = acc + bf directly: no bias_init kernel, no atomics.
__global__ __launch_bounds__(512) void stage3_kernel(
    const __hip_bfloat16* __restrict__ Hb, const float* __restrict__ wf,
    const float* __restrict__ bfv, float* __restrict__ out)
{
    __shared__ __align__(16) float sred[8 * 256];
    const int nt = blockIdx.x % 63;
    const int mh = blockIdx.x / 63;                 // 0..1: rows mh*16..mh*16+15
    const int w = threadIdx.x >> 6, lane = threadIdx.x & 63;
    const int row = lane & 15, quad = lane >> 4;
    const int c = nt * 16 + row;
    const bool cvalid = (c < 1000);
    const int kofs = w * 448 + quad * 8;
    const __hip_bfloat16* ap = Hb + (size_t)(mh * 16 + row) * 3584 + kofs;
    const float* bp = wf + (size_t)(cvalid ? c : 0) * 3584 + kofs;

    f32x4 acc = {0.f, 0.f, 0.f, 0.f};
#pragma unroll
    for (int it = 0; it < 14; ++it) {
        short8 a0 = *(const short8*)(ap + it * 32);
        float4 p0 = *(const float4*)(bp + it * 32);
        float4 p1 = *(const float4*)(bp + it * 32 + 4);
        short8 bfr;
        bfr[0] = (short)f2bf_rne(p0.x); bfr[1] = (short)f2bf_rne(p0.y);
        bfr[2] = (short)f2bf_rne(p0.z); bfr[3] = (short)f2bf_rne(p0.w);
        bfr[4] = (short)f2bf_rne(p1.x); bfr[5] = (short)f2bf_rne(p1.y);
        bfr[6] = (short)f2bf_rne(p1.z); bfr[7] = (short)f2bf_rne(p1.w);
        if (!cvalid) bfr = short8{0, 0, 0, 0, 0, 0, 0, 0};
        acc = __builtin_amdgcn_mfma_f32_16x16x32_bf16(a0, bfr, acc, 0, 0, 0);
    }
#pragma unroll
    for (int r_ = 0; r_ < 4; ++r_) sred[w * 256 + lane * 4 + r_] = acc[r_];
    __syncthreads();
    if (threadIdx.x < 64) {
        const int l2 = threadIdx.x;
        const int rr = l2 & 15, qq = l2 >> 4;
        const int cc = nt * 16 + rr;
        if (cc < 1000) {
            const float bias = bfv[cc];
#pragma unroll
            for (int r_ = 0; r_ < 4; ++r_) {
                float s = 0.f;
#pragma unroll
                for (int ww = 0; ww < 8; ++ww) s += sred[ww * 256 + l2 * 4 + r_];
                int brow = mh * 16 + qq * 4 + r_;
                out[brow * 1000 + cc] = s + bias;
            }
        }
    }
}

extern "C" void kernel_launch(void* const* d_in, const int* in_sizes, int n_in,
                              void* d_out, int out_size, void* d_ws, size_t ws_size,
                              hipStream_t stream) {
    const int* x      = (const int*)d_in[0];
    const float* emb  = (const float*)d_in[1];
    const float* w1   = (const float*)d_in[2];
    const float* b1   = (const float*)d_in[3];
    const float* w2   = (const float*)d_in[4];
    const float* b2   = (const float*)d_in[5];
    const float* wf   = (const float*)d_in[6];
    const float* bfv  = (const float*)d_in[7];

    __hip_bfloat16* H = (__hip_bfloat16*)d_ws;      // 32*3584*2 = 229,376 B

    stage12_kernel<<<32 * 64, 896, 0, stream>>>(x, emb, w1, b1, w2, b2, H);
    stage3_kernel<<<126, 512, 0, stream>>>(H, wf, bfv, (float*)d_out);
}

// Round 8
// 238.087 us; speedup vs baseline: 1.1479x; 1.0223x over previous
//
#include <hip/hip_runtime.h>
#include <hip/hip_bf16.h>

// Shapes: B=32 S=1024 D=256 V=50257 C=1000   (float tensors fp32; x int32; out fp32)
// conv1: groups=256, Cin/g=1, Cout/g=6, K=7, pad=6 -> L1=1030; fold -> 768 ch
// kmax k1=515 -> tanh -> conv2: groups=128, Cin/g=6, Cout/g=14, K=5, pad=4 -> L2=519
// fold -> 896 ch -> kmax 4 -> tanh -> (32,3584) @ wf^T(1000,3584) + bf
//
// R15 = R14 (150.8us stage12, schedule proven) + two schedule-preserving VALU cuts:
// (1) two-pass tanh/pack: compaction stores raw fkey (3-inst masked body vs 22);
// a dense full-lane pass (9 iters/wave) then converts the 515 selected entries to
// packed bf16 hi/lo in place -- bit-identical output, ~120 fewer inst/thread in the
// divergent region. (2) OUT shrunk 16->14 rows (rows 14/15 were never read; guard
// the 2 dead stores): LDS 59.9->55.6KB. No schedule changes (R13 lesson: no setprio,
// full F zero-fill stays as phase-A latency hider).

typedef __attribute__((ext_vector_type(8))) short short8;
typedef __attribute__((ext_vector_type(4))) float f32x4;
typedef __attribute__((ext_vector_type(2))) float f32x2;
typedef __attribute__((ext_vector_type(4))) int int4v;

union VPack { int4v i; short8 s; };

__device__ __forceinline__ float fast_tanh(float x) {
    float e = __expf(2.f * x);          // tanh = 1 - 2/(e^{2x}+1); saturates at +-inf
    return 1.f - 2.f / (e + 1.f);
}

__device__ __forceinline__ unsigned fkey(float f) {
    unsigned u = __float_as_uint(f);
    return (u & 0x80000000u) ? ~u : (u | 0x80000000u);   // monotone order-preserving key
}

__device__ __forceinline__ float fkey_inv(unsigned k) {
    unsigned u = (k & 0x80000000u) ? (k ^ 0x80000000u) : ~k;
    return __uint_as_float(u);
}

__device__ __forceinline__ unsigned f2bf_rne(float f) {
    unsigned u = __float_as_uint(f);
    return (u + 0x7fffu + ((u >> 16) & 1u)) >> 16;
}

// popcount of mask restricted to lanes below this lane (HW prefix-popcount)
__device__ __forceinline__ int prefix_cnt(unsigned long long m) {
    return (int)__builtin_amdgcn_mbcnt_hi((unsigned)(m >> 32),
                 __builtin_amdgcn_mbcnt_lo((unsigned)m, 0u));
}

// ---------------- Fused: gather + conv1 + fold + kmax(515) + tanh + conv2(MFMA) + fold + kmax(4) + tanh ----
// grid = 32*64 blocks (b, r2) after swizzle, 896 threads = 14 waves.
__global__ __launch_bounds__(896) void stage12_kernel(
    const int* __restrict__ x, const float* __restrict__ emb,
    const float* __restrict__ w1, const float* __restrict__ b1,
    const float* __restrict__ w2, const float* __restrict__ b2,
    __hip_bfloat16* __restrict__ H)
{
    // Region X: e[4*1104] f32 during phases A/B; OUT[14][532] f32 during phase C.
    __shared__ __align__(16) float X[7448];
    __shared__ __align__(16) unsigned F[12 * 536];  // fkey, then bf16 hi<<16|lo after pass
    const int hw = blockIdx.x;
    const int logical = ((hw & 7) << 8) | (hw >> 3);   // XCD k -> b in [4k,4k+4), all r2
    const int b = logical >> 6;
    const int r2 = logical & 63;
    const int tid = threadIdx.x;
    const int w = tid >> 6;
    const int lane = tid & 63;
    float* e = X;

    // Hoisted wave-uniform scalar loads (SGPR; latency hides under phase-A gather).
    const int half = (w >= 6) ? 1 : 0;
    const int c0 = __builtin_amdgcn_readfirstlane(
        (2 * (2 * r2 + half)) * 6 + ((w < 12) ? (w - half * 6) : 0));
    const int c1 = c0 + 6;
    float wA[7], wB[7];
#pragma unroll
    for (int t = 0; t < 7; ++t) { wA[t] = w1[c0 * 7 + t]; wB[t] = w1[c1 * 7 + t]; }
    const float bias = b1[c0] + b1[c1];
    const int bidx2 = __builtin_amdgcn_readfirstlane((2 * r2) * 14 + w);
    const float bias2 = b2[bidx2] + b2[bidx2 + 14];       // C2 bias (uniform shift)

    // Phase A: direct gather. Issue both x loads, then both scattered 16B emb loads;
    // full F zero-fill overlaps the load latency; then commit to LDS planes.
    {
        const int l0 = tid - 6;
        const int l1 = tid + 890;                   // (tid+896) - 6
        int t0 = -1, t1 = -1;
        if (l0 >= 0 && l0 < 1024) t0 = x[(b << 10) + l0];
        if (tid < 208 && l1 < 1024) t1 = x[(b << 10) + l1];
        float4 v0 = {0.f, 0.f, 0.f, 0.f}, v1 = {0.f, 0.f, 0.f, 0.f};
        if (t0 >= 0) v0 = *(const float4*)(emb + ((size_t)t0 << 8) + (r2 << 2));
        if (t1 >= 0) v1 = *(const float4*)(emb + ((size_t)t1 << 8) + (r2 << 2));
        for (int i = tid; i < 12 * 536; i += 896) F[i] = 0u;
        e[0 * 1104 + tid] = v0.x; e[1 * 1104 + tid] = v0.y;
        e[2 * 1104 + tid] = v0.z; e[3 * 1104 + tid] = v0.w;
        if (tid < 208) {
            const int idx = tid + 896;
            e[0 * 1104 + idx] = v1.x; e[1 * 1104 + idx] = v1.y;
            e[2 * 1104 + idx] = v1.z; e[3 * 1104 + idx] = v1.w;
        }
    }
    __syncthreads();

    // Phase B: waves 0..11 -> folded conv1 row i=w (packed-fp32 FMA), exact
    // radix-select 515, compact raw fkeys, then dense tanh/split/pack pass.
    if (w < 12) {
        const float* ep0 = e + (2 * half) * 1104;     // emb ch 4*r2 + 2*half
        const float* ep1 = ep0 + 1104;
        f32x2 wv[7];
#pragma unroll
        for (int t = 0; t < 7; ++t) wv[t] = f32x2{wA[t], wB[t]};

        const int pos0 = lane * 17;                   // 17 contiguous outputs/lane
        f32x2 win[7];                                 // rolling window {ch0,ch1}
#pragma unroll
        for (int t = 0; t < 7; ++t) win[t] = f32x2{ep0[pos0 + t], ep1[pos0 + t]};

        unsigned key[17];
#pragma unroll
        for (int j = 0; j < 17; ++j) {
            f32x2 acc = f32x2{bias, 0.f};
#pragma unroll
            for (int t = 0; t < 7; ++t) acc += win[t] * wv[t];   // v_pk_fma_f32
            float a = acc.x + acc.y;
            key[j] = (pos0 + j < 1030) ? fkey(a) : 0u;    // pads below any real key
            if (j < 16) {
#pragma unroll
                for (int t = 0; t < 6; ++t) win[t] = win[t + 1];
                win[6] = f32x2{ep0[pos0 + j + 7], ep1[pos0 + j + 7]};
            }
        }

        // exact radix-select of 515th-largest key; early exit when the set separates
        unsigned T = 0u;
        for (int bit = 31; bit >= 0; --bit) {
            unsigned cand = T | (1u << bit);
            int cnt = 0;
#pragma unroll
            for (int j = 0; j < 17; ++j) cnt += (int)__popcll(__ballot(key[j] >= cand));
            if (cnt >= 515) T = cand;
            if (cnt == 515) break;
        }

        // order-preserving compaction: all >T plus first (515-#gt) ==T in index order.
        // Stores RAW fkey; the dense pass below converts in place (3-inst masked body).
        int gt_tot = 0, gt_run = 0, eq_run = 0;
#pragma unroll
        for (int j = 0; j < 17; ++j) {
            unsigned long long bg = __ballot(key[j] > T);
            unsigned long long be = __ballot(key[j] == T);
            gt_tot += (int)__popcll(bg);
            gt_run += prefix_cnt(bg);
            eq_run += prefix_cnt(be);
        }
        const int q = 515 - gt_tot;
        unsigned* Frow = F + w * 536;
#pragma unroll
        for (int j = 0; j < 17; ++j) {
            bool isgt = key[j] > T;
            bool iseq = key[j] == T;
            int pos = gt_run + (eq_run < q ? eq_run : q);
            if (isgt || (iseq && eq_run < q)) Frow[4 + pos] = key[j];
            gt_run += isgt ? 1 : 0;
            eq_run += iseq ? 1 : 0;
        }

        // Dense pass: all 64 lanes, 9 iters cover positions [4,519). Same-wave DS
        // ordering (in-order LDS pipe + compiler lgkmcnt) makes this RAW-safe.
#pragma unroll
        for (int it = 0; it < 9; ++it) {
            int i = 4 + lane + (it << 6);
            if (i < 519) {
                unsigned k = Frow[i];
                float v = fast_tanh(fkey_inv(k));
                unsigned h = f2bf_rne(v);
                float fh = __uint_as_float(h << 16);
                unsigned l = f2bf_rne(v - fh);
                Frow[i] = (k == 0u) ? 0u : ((h << 16) | l);   // k==0 never selected; guard vs NaN
            }
        }
    }

    // A-fragment build (no F dependency -- before barrier so waves 12/13 overlap it
    // with phase B). k-slot (q,mm): row i = 3q + mm/5, tap t = mm%5 (mm=15 zero pad).
    const int jA = lane & 15;
    const int q3 = lane >> 4;
    short8 Ah0, Ah1, Al0, Al1;
    {
        float wt[16];
#pragma unroll
        for (int mm = 0; mm < 16; ++mm) {
            float v = 0.f;
            if (mm < 15 && jA < 14) {
                const int irow = 3 * q3 + mm / 5;          // mm/5, mm%5 compile-time
                const int t = mm % 5;
                const int h2 = (irow >= 6) ? 1 : 0;
                v = w2[(((2 * r2 + h2) * 14 + jA) * 6 + (irow - 6 * h2)) * 5 + t];
            }
            wt[mm] = v;
        }
#pragma unroll
        for (int m = 0; m < 8; ++m) {
            unsigned h0 = f2bf_rne(wt[m]);
            float fh0 = __uint_as_float(h0 << 16);
            Ah0[m] = (short)h0;
            Al0[m] = (short)f2bf_rne(wt[m] - fh0);
            unsigned h1 = f2bf_rne(wt[8 + m]);
            float fh1 = __uint_as_float(h1 << 16);
            Ah1[m] = (short)h1;
            Al1[m] = (short)f2bf_rne(wt[8 + m] - fh1);
        }
    }
    __syncthreads();

    // Phase C1: conv2+fold via split-precision MFMA. OUT[j][p] = sum_{k<60} A[j][k]*B[k][p]
    // B fragments rebuilt from packed u32 F with shift/or only (bit-identical math).
    // Lane map (verified vs stage3): A row / B col = lane&15; k-quad = lane>>4;
    // D: row = (lane>>4)*4 + r (= channel), col = lane&15 (= position).
    float* OUT = X;
    for (int tile = w; tile < 33; tile += 14) {            // 33 col-tiles over 14 waves
        const int p0 = tile << 4;
        const int bidx = (3 * q3) * 536 + p0 + jA;         // per-lane base; offsets imm
        unsigned u[16];
#pragma unroll
        for (int mm = 0; mm < 15; ++mm) u[mm] = F[bidx + (mm / 5) * 536 + (mm % 5)];
        u[15] = 0u;
        VPack bh0, bl0, bh1, bl1;
#pragma unroll
        for (int k = 0; k < 4; ++k) {
            unsigned a = u[2 * k], bq = u[2 * k + 1];
            bh0.i[k] = (int)((a >> 16) | (bq & 0xffff0000u));
            bl0.i[k] = (int)((a & 0xffffu) | (bq << 16));
            unsigned c = u[8 + 2 * k], d = u[9 + 2 * k];   // k=3 -> u[14], u[15]=0
            bh1.i[k] = (int)((c >> 16) | (d & 0xffff0000u));
            bl1.i[k] = (int)((c & 0xffffu) | (d << 16));
        }
        f32x4 d0 = {0.f, 0.f, 0.f, 0.f};
        f32x4 d1 = {0.f, 0.f, 0.f, 0.f};
        d0 = __builtin_amdgcn_mfma_f32_16x16x32_bf16(Ah0, bh0.s, d0, 0, 0, 0);
        d1 = __builtin_amdgcn_mfma_f32_16x16x32_bf16(Ah1, bh1.s, d1, 0, 0, 0);
        d0 = __builtin_amdgcn_mfma_f32_16x16x32_bf16(Ah0, bl0.s, d0, 0, 0, 0);
        d1 = __builtin_amdgcn_mfma_f32_16x16x32_bf16(Ah1, bl1.s, d1, 0, 0, 0);
        d0 = __builtin_amdgcn_mfma_f32_16x16x32_bf16(Al0, bh0.s, d0, 0, 0, 0);
        d1 = __builtin_amdgcn_mfma_f32_16x16x32_bf16(Al1, bh1.s, d1, 0, 0, 0);
        float* orow = OUT + (q3 * 4) * 532 + p0 + jA;
#pragma unroll
        for (int r = 0; r < 4; ++r)
            if (q3 * 4 + r < 14) orow[r * 532] = d0[r] + d1[r];   // rows 14,15 dead
    }
    __syncthreads();

    // Phase C2: wave w = channel j: kmax4 over OUT[j][0..519) + bias + tanh -> H
    {
        const int j = w;
        const int base = lane * 9;                            // 9 outputs/lane, 576 >= 519
        float vv[9];
#pragma unroll
        for (int jj = 0; jj < 9; ++jj)
            vv[jj] = (base + jj < 519) ? OUT[j * 532 + base + jj] : -INFINITY;
        float sv[4]; int si[4];
#pragma unroll
        for (int it = 0; it < 4; ++it) {
            float m = vv[0]; int mi = base;
#pragma unroll
            for (int jj = 1; jj < 9; ++jj) { if (vv[jj] > m) { m = vv[jj]; mi = base + jj; } }
#pragma unroll
            for (int d = 1; d < 64; d <<= 1) {
                float om = __shfl_xor(m, d, 64);
                int omi = __shfl_xor(mi, d, 64);
                if (om > m || (om == m && omi < mi)) { m = om; mi = omi; }
            }
            sv[it] = m; si[it] = mi;
            int lj = mi - base;
#pragma unroll
            for (int jj = 0; jj < 9; ++jj) if (jj == lj) vv[jj] = -INFINITY;
        }
#define CSWAP(a, bq) { if (si[a] > si[bq]) { int ti = si[a]; si[a] = si[bq]; si[bq] = ti; \
                                             float tv = sv[a]; sv[a] = sv[bq]; sv[bq] = tv; } }
        CSWAP(0, 1) CSWAP(2, 3) CSWAP(0, 2) CSWAP(1, 3) CSWAP(1, 2)
#undef CSWAP
        if (lane == 0) {
            __hip_bfloat16* op = H + (size_t)b * 3584 + (r2 * 14 + j) * 4;
#pragma unroll
            for (int k = 0; k < 4; ++k) op[k] = __float2bfloat16(fast_tanh(sv[k] + bias2));
        }
    }
}

// ---------------- Stage 3: (32x3584) @ wf^T (3584x1000) + bf via MFMA, full K per block ----
// grid = 63 col-tiles x 2 M-halves = 126 blocks, 512 thr (8 waves split K, LDS reduce).
// Writes out = acc + bf directly: no bias_init kernel, no atomics.
__global__ __launch_bounds__(512) void stage3_kernel(
    const __hip_bfloat16* __restrict__ Hb, const float* __restrict__ wf,
    const float* __restrict__ bfv, float* __restrict__ out)
{
    __shared__ __align__(16) float sred[8 * 256];
    const int nt = blockIdx.x % 63;
    const int mh = blockIdx.x / 63;                 // 0..1: rows mh*16..mh*16+15
    const int w = threadIdx.x >> 6, lane = threadIdx.x & 63;
    const int row = lane & 15, quad = lane >> 4;
    const int c = nt * 16 + row;
    const bool cvalid = (c < 1000);
    const int kofs = w * 448 + quad * 8;
    const __hip_bfloat16* ap = Hb + (size_t)(mh * 16 + row) * 3584 + kofs;
    const float* bp = wf + (size_t)(cvalid ? c : 0) * 3584 + kofs;

    f32x4 acc = {0.f, 0.f, 0.f, 0.f};
#pragma unroll
    for (int it = 0; it < 14; ++it) {
        short8 a0 = *(const short8*)(ap + it * 32);
        float4 p0 = *(const float4*)(bp + it * 32);
        float4 p1 = *(const float4*)(bp + it * 32 + 4);
        short8 bfr;
        bfr[0] = (short)f2bf_rne(p0.x); bfr[1] = (short)f2bf_rne(p0.y);
        bfr[2] = (short)f2bf_rne(p0.z); bfr[3] = (short)f2bf_rne(p0.w);
        bfr[4] = (short)f2bf_rne(p1.x); bfr[5] = (short)f2bf_rne(p1.y);
        bfr[6] = (short)f2bf_rne(p1.z); bfr[7] = (short)f2bf_rne(p1.w);
        if (!cvalid) bfr = short8{0, 0, 0, 0, 0, 0, 0, 0};
        acc = __builtin_amdgcn_mfma_f32_16x16x32_bf16(a0, bfr, acc, 0, 0, 0);
    }
#pragma unroll
    for (int r_ = 0; r_ < 4; ++r_) sred[w * 256 + lane * 4 + r_] = acc[r_];
    __syncthreads();
    if (threadIdx.x < 64) {
        const int l2 = threadIdx.x;
        const int rr = l2 & 15, qq = l2 >> 4;
        const int cc = nt * 16 + rr;
        if (cc < 1000) {
            const float bias = bfv[cc];
#pragma unroll
            for (int r_ = 0; r_ < 4; ++r_) {
                float s = 0.f;
#pragma unroll
                for (int ww = 0; ww < 8; ++ww) s += sred[ww * 256 + l2 * 4 + r_];
                int brow = mh * 16 + qq * 4 + r_;
                out[brow * 1000 + cc] = s + bias;
            }
        }
    }
}

extern "C" void kernel_launch(void* const* d_in, const int* in_sizes, int n_in,
                              void* d_out, int out_size, void* d_ws, size_t ws_size,
                              hipStream_t stream) {
    const int* x      = (const int*)d_in[0];
    const float* emb  = (const float*)d_in[1];
    const float* w1   = (const float*)d_in[2];
    const float* b1   = (const float*)d_in[3];
    const float* w2   = (const float*)d_in[4];
    const float* b2   = (const float*)d_in[5];
    const float* wf   = (const float*)d_in[6];
    const float* bfv  = (const float*)d_in[7];

    __hip_bfloat16* H = (__hip_bfloat16*)d_ws;      // 32*3584*2 = 229,376 B

    stage12_kernel<<<32 * 64, 896, 0, stream>>>(x, emb, w1, b1, w2, b2, H);
    stage3_kernel<<<126, 512, 0, stream>>>(H, wf, bfv, (float*)d_out);
}